// Round 1
// baseline (1500.753 us; speedup 1.0000x reference)
//
#include <hip/hip_runtime.h>
#include <math.h>

#define TPB 256

// ---------------------------------------------------------------- utilities
__global__ void deg_kernel(const int* __restrict__ dst, float* __restrict__ deg, int E) {
    int i = blockIdx.x * blockDim.x + threadIdx.x;
    int stride = gridDim.x * blockDim.x;
    for (; i < E; i += stride) atomicAdd(&deg[dst[i]], 1.0f);
}

__global__ void dinv_kernel(float* __restrict__ deg, int n) {
    int i = blockIdx.x * blockDim.x + threadIdx.x;
    if (i < n) deg[i] = rsqrtf(deg[i] + 1.0f);
}

// ------------------------------------------------- GEMM: Y = (X@W)*dinv[row]
// Also writes ACC = Y (self-loop init). W staged in LDS in K-chunks (<=32KB).
// Each thread computes 4 rows x 16 cols.
template<int K, int NCOL>
__global__ __launch_bounds__(TPB) void gemm_scale(
    const float* __restrict__ X, const float* __restrict__ W,
    const float* __restrict__ dinv, float* __restrict__ Y,
    float* __restrict__ ACC, int nrows)
{
    constexpr int CG   = NCOL / 16;      // threads cooperating per row
    constexpr int TR   = TPB / CG;       // thread-rows per block
    constexpr int ROWS = TR * 4;         // rows per block
    constexpr int KC   = (K * NCOL <= 8192) ? K : (8192 / NCOL);  // <=32KB LDS
    __shared__ float wlds[KC * NCOL];

    const int t    = threadIdx.x;
    const int q    = t % CG;
    const int tr   = t / CG;
    const int row0 = blockIdx.x * ROWS + tr;

    float4 acc[4][4];
#pragma unroll
    for (int i = 0; i < 4; i++)
#pragma unroll
        for (int j = 0; j < 4; j++) acc[i][j] = make_float4(0.f, 0.f, 0.f, 0.f);

    for (int k0 = 0; k0 < K; k0 += KC) {
        __syncthreads();
        for (int i = t; i < KC * NCOL / 4; i += TPB)
            ((float4*)wlds)[i] = ((const float4*)(W + (size_t)k0 * NCOL))[i];
        __syncthreads();

        for (int k = 0; k < KC; k += 4) {
            float4 xv[4];
#pragma unroll
            for (int i = 0; i < 4; i++) {
                int r = row0 + i * TR;
                xv[i] = (r < nrows) ? *(const float4*)(X + (size_t)r * K + k0 + k)
                                    : make_float4(0.f, 0.f, 0.f, 0.f);
            }
#pragma unroll
            for (int kk = 0; kk < 4; kk++) {
                float4 w[4];
#pragma unroll
                for (int j = 0; j < 4; j++)
                    w[j] = *(const float4*)(wlds + (k + kk) * NCOL + q * 16 + j * 4);
#pragma unroll
                for (int i = 0; i < 4; i++) {
                    float xs = (kk == 0) ? xv[i].x : (kk == 1) ? xv[i].y
                             : (kk == 2) ? xv[i].z : xv[i].w;
#pragma unroll
                    for (int j = 0; j < 4; j++) {
                        acc[i][j].x = fmaf(xs, w[j].x, acc[i][j].x);
                        acc[i][j].y = fmaf(xs, w[j].y, acc[i][j].y);
                        acc[i][j].z = fmaf(xs, w[j].z, acc[i][j].z);
                        acc[i][j].w = fmaf(xs, w[j].w, acc[i][j].w);
                    }
                }
            }
        }
    }

#pragma unroll
    for (int i = 0; i < 4; i++) {
        int r = row0 + i * TR;
        if (r < nrows) {
            float dv = dinv[r];
#pragma unroll
            for (int j = 0; j < 4; j++) {
                float4 v = acc[i][j];
                v.x *= dv; v.y *= dv; v.z *= dv; v.w *= dv;
                *(float4*)(Y   + (size_t)r * NCOL + q * 16 + j * 4) = v;
                *(float4*)(ACC + (size_t)r * NCOL + q * 16 + j * 4) = v;
            }
        }
    }
}

// ---------------------------------------- edge scatter: acc[dst] += y[src]
// Wave-cooperative: lanes span the feature dim (coalesced gather + atomics).
// Each wave batches 64 edge indices into registers, broadcasts via shfl.
template<int F>
__global__ __launch_bounds__(TPB) void edge_agg(
    const int* __restrict__ src, const int* __restrict__ dst,
    const float* __restrict__ y, float* __restrict__ acc, int E)
{
    constexpr int EPW   = 64 / F;                       // edges per inner step
    constexpr int LOG2F = (F == 64) ? 6 : (F == 32) ? 5 : 4;
    const int lane = threadIdx.x & 63;
    const int wid  = (blockIdx.x * blockDim.x + threadIdx.x) >> 6;
    const int nw   = (gridDim.x * blockDim.x) >> 6;
    const int f    = lane & (F - 1);
    const int sub  = lane >> LOG2F;

    for (int base = wid * 64; base < E; base += nw * 64) {
        int e = base + lane;
        int s = -1, d = 0;
        if (e < E) { s = src[e]; d = dst[e]; }
#pragma unroll 4
        for (int j = 0; j < 64; j += EPW) {
            int sj = __shfl(s, j + sub, 64);
            int dj = __shfl(d, j + sub, 64);
            if (sj >= 0)
                atomicAdd(&acc[dj * F + f], y[sj * F + f]);
        }
    }
}

// ------------------------------------- H = relu(dinv[row]*ACC + b[col])
template<int F>
__global__ __launch_bounds__(TPB) void finish_kernel(
    const float* __restrict__ ACC, const float* __restrict__ dinv,
    const float* __restrict__ b, float* __restrict__ H, int n)
{
    int i = blockIdx.x * blockDim.x + threadIdx.x;
    int stride = gridDim.x * blockDim.x;
    int total = n * F / 4;
    for (; i < total; i += stride) {
        float4 a = ((const float4*)ACC)[i];
        int row = (i * 4) / F;
        int col = (i * 4) % F;
        float dv = dinv[row];
        float4 r;
        r.x = fmaxf(fmaf(a.x, dv, b[col + 0]), 0.f);
        r.y = fmaxf(fmaf(a.y, dv, b[col + 1]), 0.f);
        r.z = fmaxf(fmaf(a.z, dv, b[col + 2]), 0.f);
        r.w = fmaxf(fmaf(a.w, dv, b[col + 3]), 0.f);
        ((float4*)H)[i] = r;
    }
}

// ------------------------------------------------- mean pool (sum -> atomic)
__global__ __launch_bounds__(TPB) void pool_kernel(
    const float* __restrict__ H, float* __restrict__ pooled, int n)
{
    const int f = threadIdx.x & 15;
    int r = (blockIdx.x * blockDim.x + threadIdx.x) >> 4;
    const int rstride = (gridDim.x * blockDim.x) >> 4;
    float s = 0.f;
    for (; r < n; r += rstride) s += H[r * 16 + f];
    __shared__ float red[TPB];
    red[threadIdx.x] = s;
    __syncthreads();
    if (threadIdx.x < 16) {
        float tot = 0.f;
        for (int i = threadIdx.x; i < TPB; i += 16) tot += red[i];
        atomicAdd(&pooled[threadIdx.x], tot);
    }
}

// --------------------------------------------------- tiny MLP head + logsoftmax
__global__ void head_kernel(const float* __restrict__ pooled,
                            const float* __restrict__ Wf, const float* __restrict__ bf,
                            const float* __restrict__ Ws, const float* __restrict__ bs,
                            float* __restrict__ out, float invn)
{
    if (threadIdx.x == 0 && blockIdx.x == 0) {
        float p[16], h[8], s[10];
        for (int i = 0; i < 16; i++) p[i] = pooled[i] * invn;
        for (int j = 0; j < 8; j++) {
            float a = bf[j];
            for (int i = 0; i < 16; i++) a = fmaf(p[i], Wf[i * 8 + j], a);
            h[j] = fmaxf(a, 0.f);
        }
        float m = -1e30f;
        for (int c = 0; c < 10; c++) {
            float a = bs[c];
            for (int j = 0; j < 8; j++) a = fmaf(h[j], Ws[j * 10 + c], a);
            s[c] = a;
            m = fmaxf(m, a);
        }
        float lse = 0.f;
        for (int c = 0; c < 10; c++) lse += expf(s[c] - m);
        lse = logf(lse) + m;
        for (int c = 0; c < 10; c++) out[c] = s[c] - lse;
    }
}

static inline size_t align_up(size_t x) { return (x + 255) & ~(size_t)255; }

extern "C" void kernel_launch(void* const* d_in, const int* in_sizes, int n_in,
                              void* d_out, int out_size, void* d_ws, size_t ws_size,
                              hipStream_t stream)
{
    const float* X  = (const float*)d_in[0];
    const int*   ei = (const int*)  d_in[1];
    const float* W1 = (const float*)d_in[2];  const float* b1 = (const float*)d_in[3];
    const float* W2 = (const float*)d_in[4];  const float* b2 = (const float*)d_in[5];
    const float* W3 = (const float*)d_in[6];  const float* b3 = (const float*)d_in[7];
    const float* Wf = (const float*)d_in[8];  const float* bf = (const float*)d_in[9];
    const float* Ws = (const float*)d_in[10]; const float* bs = (const float*)d_in[11];

    const int n = in_sizes[0] / 256;
    const int E = in_sizes[1] / 2;
    const int* src = ei;
    const int* dst = ei + E;

    // workspace layout: dinv | bufA (n*64) | bufB (n*64) | pooled(16)
    char* ws = (char*)d_ws;
    float* dinv = (float*)ws;
    size_t off = align_up((size_t)n * 4);
    float* bufA = (float*)(ws + off);
    off += align_up((size_t)n * 64 * 4);
    float* bufB = (float*)(ws + off);
    off += align_up((size_t)n * 64 * 4);
    float* pooled = (float*)(ws + off);

    hipMemsetAsync(dinv, 0, (size_t)n * 4, stream);
    hipMemsetAsync(pooled, 0, 16 * 4, stream);

    deg_kernel<<<2048, TPB, 0, stream>>>(dst, dinv, E);
    dinv_kernel<<<(n + TPB - 1) / TPB, TPB, 0, stream>>>(dinv, n);

    // ---- layer 1: 256 -> 64
    gemm_scale<256, 64><<<(n + 255) / 256, TPB, 0, stream>>>(X, W1, dinv, bufA, bufB, n);
    edge_agg<64><<<4096, TPB, 0, stream>>>(src, dst, bufA, bufB, E);
    finish_kernel<64><<<2048, TPB, 0, stream>>>(bufB, dinv, b1, bufA, n);   // H1 -> bufA

    // ---- layer 2: 64 -> 32
    float* Y2   = bufB;
    float* ACC2 = bufB + (size_t)n * 32;
    gemm_scale<64, 32><<<(n + 511) / 512, TPB, 0, stream>>>(bufA, W2, dinv, Y2, ACC2, n);
    edge_agg<32><<<4096, TPB, 0, stream>>>(src, dst, Y2, ACC2, E);
    finish_kernel<32><<<2048, TPB, 0, stream>>>(ACC2, dinv, b2, bufA, n);   // H2 -> bufA

    // ---- layer 3: 32 -> 16
    float* Y3   = bufB;
    float* ACC3 = bufB + (size_t)n * 16;
    gemm_scale<32, 16><<<(n + 1023) / 1024, TPB, 0, stream>>>(bufA, W3, dinv, Y3, ACC3, n);
    edge_agg<16><<<4096, TPB, 0, stream>>>(src, dst, Y3, ACC3, E);
    finish_kernel<16><<<2048, TPB, 0, stream>>>(ACC3, dinv, b3, bufA, n);   // H3 -> bufA

    // ---- pool + head
    pool_kernel<<<256, TPB, 0, stream>>>(bufA, pooled, n);
    head_kernel<<<1, 64, 0, stream>>>(pooled, Wf, bf, Ws, bs, (float*)d_out, 1.0f / (float)n);
}

// Round 2
// 940.774 us; speedup vs baseline: 1.5952x; 1.5952x over previous
//
#include <hip/hip_runtime.h>
#include <math.h>

#define TPB 256

// ---------------------------------------------------------------- degree histogram (int)
__global__ void deg_hist(const int* __restrict__ dst, int* __restrict__ deg, int E) {
    int i = blockIdx.x * blockDim.x + threadIdx.x;
    int stride = gridDim.x * blockDim.x;
    for (; i < E; i += stride) atomicAdd(&deg[dst[i]], 1);
}

// ---------------------------------------------------------------- 3-phase exclusive scan
// phase 1: per-block (1024 elems) sums
__global__ __launch_bounds__(256) void scan_sum(const int* __restrict__ deg,
                                                int* __restrict__ bsum, int n) {
    int t = threadIdx.x;
    int base = blockIdx.x * 1024;
    int s = 0;
    for (int i = t; i < 1024; i += 256) {
        int idx = base + i;
        if (idx < n) s += deg[idx];
    }
    __shared__ int red[256];
    red[t] = s; __syncthreads();
    for (int st = 128; st > 0; st >>= 1) {
        if (t < st) red[t] += red[t + st];
        __syncthreads();
    }
    if (t == 0) bsum[blockIdx.x] = red[0];
}

// phase 2: scan the block partials (nb <= 256)
__global__ __launch_bounds__(256) void scan_partials(const int* __restrict__ bsum,
                                                     int* __restrict__ bpre, int nb) {
    int t = threadIdx.x;
    int v = (t < nb) ? bsum[t] : 0;
    __shared__ int tmp[256];
    tmp[t] = v; __syncthreads();
    for (int s = 1; s < 256; s <<= 1) {
        int x = (t >= s) ? tmp[t - s] : 0;
        __syncthreads();
        tmp[t] += x;
        __syncthreads();
    }
    if (t < nb) bpre[t] = tmp[t] - v;
}

// phase 3: full exclusive scan -> off, cursor; also dinv = rsqrt(deg+1)
__global__ __launch_bounds__(256) void scan_final(
    const int* __restrict__ deg, const int* __restrict__ bpre,
    int* __restrict__ off, int* __restrict__ cursor,
    float* __restrict__ dinv, int n)
{
    int t = threadIdx.x;
    int base = blockIdx.x * 1024;
    int i0 = base + t * 4;
    int vals[4] = {0, 0, 0, 0};
    if (i0 + 3 < n) {
        int4 v = *(const int4*)(deg + i0);
        vals[0] = v.x; vals[1] = v.y; vals[2] = v.z; vals[3] = v.w;
    } else {
        for (int k = 0; k < 4; k++) if (i0 + k < n) vals[k] = deg[i0 + k];
    }
    int tsum = vals[0] + vals[1] + vals[2] + vals[3];
    __shared__ int tmp[256];
    tmp[t] = tsum; __syncthreads();
    for (int s = 1; s < 256; s <<= 1) {
        int x = (t >= s) ? tmp[t - s] : 0;
        __syncthreads();
        tmp[t] += x;
        __syncthreads();
    }
    int run = tmp[t] - tsum + bpre[blockIdx.x];
    for (int k = 0; k < 4; k++) {
        int i = i0 + k;
        if (i < n) {
            off[i] = run;
            cursor[i] = run;
            dinv[i] = rsqrtf((float)vals[k] + 1.0f);
            run += vals[k];
            if (i == n - 1) off[n] = run;
        }
    }
}

// ---------------------------------------------------------------- counting-sort scatter
__global__ __launch_bounds__(TPB) void scatter_edges(
    const int* __restrict__ src, const int* __restrict__ dst,
    int* __restrict__ cursor, int* __restrict__ ssrc, int E)
{
    int i = blockIdx.x * blockDim.x + threadIdx.x;
    int stride = gridDim.x * blockDim.x;
    for (; i < E; i += stride) {
        int d = dst[i];
        int pos = atomicAdd(&cursor[d], 1);
        ssrc[pos] = src[i];
    }
}

// ------------------------------------------------- GEMM: Y = (X@W)*dinv[row]
// W staged in LDS in K-chunks. Each thread computes 4 rows x 16 cols.
template<int K, int NCOL>
__global__ __launch_bounds__(TPB) void gemm_scale(
    const float* __restrict__ X, const float* __restrict__ W,
    const float* __restrict__ dinv, float* __restrict__ Y, int nrows)
{
    constexpr int CG   = NCOL / 16;
    constexpr int TR   = TPB / CG;
    constexpr int ROWS = TR * 4;
    constexpr int KC   = (K * NCOL <= 8192) ? K : (8192 / NCOL);
    __shared__ float wlds[KC * NCOL];

    const int t    = threadIdx.x;
    const int q    = t % CG;
    const int tr   = t / CG;
    const int row0 = blockIdx.x * ROWS + tr;

    float4 acc[4][4];
#pragma unroll
    for (int i = 0; i < 4; i++)
#pragma unroll
        for (int j = 0; j < 4; j++) acc[i][j] = make_float4(0.f, 0.f, 0.f, 0.f);

    for (int k0 = 0; k0 < K; k0 += KC) {
        __syncthreads();
        for (int i = t; i < KC * NCOL / 4; i += TPB)
            ((float4*)wlds)[i] = ((const float4*)(W + (size_t)k0 * NCOL))[i];
        __syncthreads();

        for (int k = 0; k < KC; k += 4) {
            float4 xv[4];
#pragma unroll
            for (int i = 0; i < 4; i++) {
                int r = row0 + i * TR;
                xv[i] = (r < nrows) ? *(const float4*)(X + (size_t)r * K + k0 + k)
                                    : make_float4(0.f, 0.f, 0.f, 0.f);
            }
#pragma unroll
            for (int kk = 0; kk < 4; kk++) {
                float4 w[4];
#pragma unroll
                for (int j = 0; j < 4; j++)
                    w[j] = *(const float4*)(wlds + (k + kk) * NCOL + q * 16 + j * 4);
#pragma unroll
                for (int i = 0; i < 4; i++) {
                    float xs = (kk == 0) ? xv[i].x : (kk == 1) ? xv[i].y
                             : (kk == 2) ? xv[i].z : xv[i].w;
#pragma unroll
                    for (int j = 0; j < 4; j++) {
                        acc[i][j].x = fmaf(xs, w[j].x, acc[i][j].x);
                        acc[i][j].y = fmaf(xs, w[j].y, acc[i][j].y);
                        acc[i][j].z = fmaf(xs, w[j].z, acc[i][j].z);
                        acc[i][j].w = fmaf(xs, w[j].w, acc[i][j].w);
                    }
                }
            }
        }
    }

#pragma unroll
    for (int i = 0; i < 4; i++) {
        int r = row0 + i * TR;
        if (r < nrows) {
            float dv = dinv[r];
#pragma unroll
            for (int j = 0; j < 4; j++) {
                float4 v = acc[i][j];
                v.x *= dv; v.y *= dv; v.z *= dv; v.w *= dv;
                *(float4*)(Y + (size_t)r * NCOL + q * 16 + j * 4) = v;
            }
        }
    }
}

// ---------------------------------------- pull-mode segment aggregation, fused epilogue
// H[v] = relu(dinv[v]*(sum_{src in seg(v)} y[src] + y[v]) + b)
// sub-wave of F lanes per node; ssrc segment is contiguous (dst-sorted).
template<int F>
__global__ __launch_bounds__(TPB) void seg_agg(
    const int* __restrict__ off, const int* __restrict__ ssrc,
    const float* __restrict__ y, const float* __restrict__ dinv,
    const float* __restrict__ b, float* __restrict__ H, int n)
{
    constexpr int LOG2F = (F == 64) ? 6 : (F == 32) ? 5 : 4;
    constexpr int NPW   = 64 / F;
    const int lane = threadIdx.x & 63;
    const int f    = lane & (F - 1);
    const int sub  = lane >> LOG2F;
    const int wid  = (blockIdx.x * blockDim.x + threadIdx.x) >> 6;
    const int nw   = (gridDim.x * blockDim.x) >> 6;
    const float bv = b[f];

    for (int v0 = wid * NPW; v0 < n; v0 += nw * NPW) {
        int v = v0 + sub;
        if (v < n) {
            int e0 = off[v], e1 = off[v + 1];
            float s = y[v * F + f];                       // self loop
            for (int base = e0; base < e1; base += F) {
                int idx = (base + f < e1) ? ssrc[base + f] : 0;
                int cnt = min(F, e1 - base);
                for (int j = 0; j < cnt; j++) {
                    int sj = __shfl(idx, sub * F + j, 64);
                    s += y[sj * F + f];
                }
            }
            H[v * F + f] = fmaxf(fmaf(s, dinv[v], bv), 0.f);
        }
    }
}

// layer-3 variant: no H write; fuse mean-pool accumulation (F=16)
__global__ __launch_bounds__(TPB) void seg_agg16_pool(
    const int* __restrict__ off, const int* __restrict__ ssrc,
    const float* __restrict__ y, const float* __restrict__ dinv,
    const float* __restrict__ b, float* __restrict__ pooled, int n)
{
    const int lane = threadIdx.x & 63;
    const int f    = lane & 15;
    const int sub  = lane >> 4;
    const int wid  = (blockIdx.x * blockDim.x + threadIdx.x) >> 6;
    const int nw   = (gridDim.x * blockDim.x) >> 6;
    const float bv = b[f];
    float pacc = 0.f;

    for (int v0 = wid * 4; v0 < n; v0 += nw * 4) {
        int v = v0 + sub;
        if (v < n) {
            int e0 = off[v], e1 = off[v + 1];
            float s = y[v * 16 + f];
            for (int base = e0; base < e1; base += 16) {
                int idx = (base + f < e1) ? ssrc[base + f] : 0;
                int cnt = min(16, e1 - base);
                for (int j = 0; j < cnt; j++) {
                    int sj = __shfl(idx, sub * 16 + j, 64);
                    s += y[sj * 16 + f];
                }
            }
            pacc += fmaxf(fmaf(s, dinv[v], bv), 0.f);
        }
    }
    __shared__ float red[TPB];
    red[threadIdx.x] = pacc; __syncthreads();
    for (int st = 128; st >= 16; st >>= 1) {
        if (threadIdx.x < st) red[threadIdx.x] += red[threadIdx.x + st];
        __syncthreads();
    }
    if (threadIdx.x < 16) atomicAdd(&pooled[threadIdx.x], red[threadIdx.x]);
}

// --------------------------------------------------- tiny MLP head + logsoftmax
__global__ void head_kernel(const float* __restrict__ pooled,
                            const float* __restrict__ Wf, const float* __restrict__ bf,
                            const float* __restrict__ Ws, const float* __restrict__ bs,
                            float* __restrict__ out, float invn)
{
    if (threadIdx.x == 0 && blockIdx.x == 0) {
        float p[16], h[8], s[10];
        for (int i = 0; i < 16; i++) p[i] = pooled[i] * invn;
        for (int j = 0; j < 8; j++) {
            float a = bf[j];
            for (int i = 0; i < 16; i++) a = fmaf(p[i], Wf[i * 8 + j], a);
            h[j] = fmaxf(a, 0.f);
        }
        float m = -1e30f;
        for (int c = 0; c < 10; c++) {
            float a = bs[c];
            for (int j = 0; j < 8; j++) a = fmaf(h[j], Ws[j * 10 + c], a);
            s[c] = a;
            m = fmaxf(m, a);
        }
        float lse = 0.f;
        for (int c = 0; c < 10; c++) lse += expf(s[c] - m);
        lse = logf(lse) + m;
        for (int c = 0; c < 10; c++) out[c] = s[c] - lse;
    }
}

static inline size_t align_up(size_t x) { return (x + 255) & ~(size_t)255; }

extern "C" void kernel_launch(void* const* d_in, const int* in_sizes, int n_in,
                              void* d_out, int out_size, void* d_ws, size_t ws_size,
                              hipStream_t stream)
{
    const float* X  = (const float*)d_in[0];
    const int*   ei = (const int*)  d_in[1];
    const float* W1 = (const float*)d_in[2];  const float* b1 = (const float*)d_in[3];
    const float* W2 = (const float*)d_in[4];  const float* b2 = (const float*)d_in[5];
    const float* W3 = (const float*)d_in[6];  const float* b3 = (const float*)d_in[7];
    const float* Wf = (const float*)d_in[8];  const float* bf = (const float*)d_in[9];
    const float* Ws = (const float*)d_in[10]; const float* bs = (const float*)d_in[11];

    const int n = in_sizes[0] / 256;
    const int E = in_sizes[1] / 2;
    const int* src = ei;
    const int* dst = ei + E;

    // workspace layout
    char* ws = (char*)d_ws;
    size_t off_b = 0;
    int* deg    = (int*)(ws + off_b);   off_b += align_up((size_t)n * 4);
    float* dinv = (float*)(ws + off_b); off_b += align_up((size_t)n * 4);
    int* off    = (int*)(ws + off_b);   off_b += align_up((size_t)(n + 1) * 4);
    int* cursor = (int*)(ws + off_b);   off_b += align_up((size_t)n * 4);
    int* bsum   = (int*)(ws + off_b);   off_b += align_up(256 * 4);
    int* bpre   = (int*)(ws + off_b);   off_b += align_up(256 * 4);
    float* pooled = (float*)(ws + off_b); off_b += align_up(16 * 4);
    int* ssrc   = (int*)(ws + off_b);   off_b += align_up((size_t)E * 4);
    float* Y    = (float*)(ws + off_b); off_b += align_up((size_t)n * 64 * 4);
    float* H    = (float*)(ws + off_b); off_b += align_up((size_t)n * 64 * 4);

    hipMemsetAsync(deg, 0, (size_t)n * 4, stream);
    hipMemsetAsync(pooled, 0, 16 * 4, stream);

    const int nb = (n + 1023) / 1024;

    // graph preprocessing (once; reused by all 3 layers)
    deg_hist<<<1024, TPB, 0, stream>>>(dst, deg, E);
    scan_sum<<<nb, 256, 0, stream>>>(deg, bsum, n);
    scan_partials<<<1, 256, 0, stream>>>(bsum, bpre, nb);
    scan_final<<<nb, 256, 0, stream>>>(deg, bpre, off, cursor, dinv, n);
    scatter_edges<<<1024, TPB, 0, stream>>>(src, dst, cursor, ssrc, E);

    // ---- layer 1: 256 -> 64
    gemm_scale<256, 64><<<(n + 255) / 256, TPB, 0, stream>>>(X, W1, dinv, Y, n);
    seg_agg<64><<<2048, TPB, 0, stream>>>(off, ssrc, Y, dinv, b1, H, n);

    // ---- layer 2: 64 -> 32
    gemm_scale<64, 32><<<(n + 511) / 512, TPB, 0, stream>>>(H, W2, dinv, Y, n);
    seg_agg<32><<<2048, TPB, 0, stream>>>(off, ssrc, Y, dinv, b2, H, n);

    // ---- layer 3: 32 -> 16 (fused pool)
    gemm_scale<32, 16><<<(n + 1023) / 1024, TPB, 0, stream>>>(H, W3, dinv, Y, n);
    seg_agg16_pool<<<1024, TPB, 0, stream>>>(off, ssrc, Y, dinv, b3, pooled, n);

    head_kernel<<<1, 64, 0, stream>>>(pooled, Wf, bf, Ws, bs, (float*)d_out, 1.0f / (float)n);
}

// Round 3
// 633.525 us; speedup vs baseline: 2.3689x; 1.4850x over previous
//
#include <hip/hip_runtime.h>
#include <math.h>

#define TPB 256
#define BKT_SHIFT 9
#define BKT_N 512              // nodes per bucket
#define NB_MAX 256             // max buckets (n <= 131072)
#define CHUNK 8192             // edges per block-chunk in bucket_scatter

// ---------------------------------------------------------------- pass A0: bucket sizes
__global__ __launch_bounds__(TPB) void bucket_count(
    const int* __restrict__ dst, int* __restrict__ bsize, int E, int nbkt)
{
    __shared__ int h[NB_MAX];
    for (int i = threadIdx.x; i < nbkt; i += TPB) h[i] = 0;
    __syncthreads();
    for (int i = blockIdx.x * TPB + threadIdx.x; i < E; i += gridDim.x * TPB)
        atomicAdd(&h[dst[i] >> BKT_SHIFT], 1);
    __syncthreads();
    for (int i = threadIdx.x; i < nbkt; i += TPB)
        if (h[i]) atomicAdd(&bsize[i], h[i]);
}

// ---------------------------------------------------------------- bucket offsets (1 block)
__global__ __launch_bounds__(256) void bucket_scan(
    const int* __restrict__ bsize, int* __restrict__ boff,
    int* __restrict__ bcursor, int nbkt, int E)
{
    int t = threadIdx.x;
    int v = (t < nbkt) ? bsize[t] : 0;
    __shared__ int tmp[256];
    tmp[t] = v; __syncthreads();
    for (int s = 1; s < 256; s <<= 1) {
        int x = (t >= s) ? tmp[t - s] : 0;
        __syncthreads();
        tmp[t] += x;
        __syncthreads();
    }
    if (t < nbkt) { boff[t] = tmp[t] - v; bcursor[t] = tmp[t] - v; }
    if (t == 0) boff[nbkt] = E;
}

// ---------------------------------------------------------------- pass A1: bucketed scatter
// packed edge: (dst_local << 17) | src   (src < 2^17, dst_local < 2^9)
__global__ __launch_bounds__(TPB) void bucket_scatter(
    const int* __restrict__ src, const int* __restrict__ dst,
    int* __restrict__ bcursor, unsigned int* __restrict__ packed, int E, int nbkt)
{
    __shared__ int h[NB_MAX];
    __shared__ int base[NB_MAX];
    for (int c0 = blockIdx.x * CHUNK; c0 < E; c0 += gridDim.x * CHUNK) {
        int c1 = min(c0 + CHUNK, E);
        for (int i = threadIdx.x; i < nbkt; i += TPB) h[i] = 0;
        __syncthreads();
        for (int i = c0 + threadIdx.x; i < c1; i += TPB)
            atomicAdd(&h[dst[i] >> BKT_SHIFT], 1);
        __syncthreads();
        for (int i = threadIdx.x; i < nbkt; i += TPB) {
            int c = h[i];
            base[i] = c ? atomicAdd(&bcursor[i], c) : 0;
            h[i] = 0;
        }
        __syncthreads();
        for (int i = c0 + threadIdx.x; i < c1; i += TPB) {
            int d = dst[i];
            int b = d >> BKT_SHIFT;
            int pos = base[b] + atomicAdd(&h[b], 1);
            packed[pos] = ((unsigned)(d & (BKT_N - 1)) << 17) | (unsigned)src[i];
        }
        __syncthreads();
    }
}

// ---------------------------------------------------------------- pass B: per-bucket CSR
// one block per bucket: LDS hist -> LDS scan -> off/dinv, then LDS-cursor scatter of ssrc
__global__ __launch_bounds__(256) void bucket_csr(
    const unsigned int* __restrict__ packed, const int* __restrict__ boff,
    int* __restrict__ off, float* __restrict__ dinv, int* __restrict__ ssrc,
    int n, int nbkt)
{
    const int b  = blockIdx.x;
    const int e0 = boff[b], e1 = boff[b + 1];
    const int v0 = b << BKT_SHIFT;
    const int nv = min(BKT_N, n - v0);
    const int t  = threadIdx.x;

    __shared__ int hist[BKT_N];
    __shared__ int cur[BKT_N];
    __shared__ int tmp[256];

    for (int i = t; i < nv; i += 256) hist[i] = 0;
    __syncthreads();
    for (int e = e0 + t; e < e1; e += 256)
        atomicAdd(&hist[packed[e] >> 17], 1);
    __syncthreads();

    // exclusive scan of hist[0..nv) with 256 threads x 2 elements
    int a = (2 * t     < nv) ? hist[2 * t]     : 0;
    int c = (2 * t + 1 < nv) ? hist[2 * t + 1] : 0;
    int ps = a + c;
    tmp[t] = ps; __syncthreads();
    for (int s = 1; s < 256; s <<= 1) {
        int x = (t >= s) ? tmp[t - s] : 0;
        __syncthreads();
        tmp[t] += x;
        __syncthreads();
    }
    int ex = tmp[t] - ps;
    if (2 * t < nv) {
        cur[2 * t] = ex;
        off[v0 + 2 * t] = e0 + ex;
        dinv[v0 + 2 * t] = rsqrtf((float)a + 1.0f);
    }
    if (2 * t + 1 < nv) {
        cur[2 * t + 1] = ex + a;
        off[v0 + 2 * t + 1] = e0 + ex + a;
        dinv[v0 + 2 * t + 1] = rsqrtf((float)c + 1.0f);
    }
    if (b == nbkt - 1 && t == 0) off[n] = e1;
    __syncthreads();

    for (int e = e0 + t; e < e1; e += 256) {
        unsigned p = packed[e];
        int dl = p >> 17;
        int s  = p & 0x1FFFF;
        int pos = atomicAdd(&cur[dl], 1);
        ssrc[e0 + pos] = s;
    }
}

// ------------------------------------------------- GEMM: Y = (X@W)*dinv[row]
template<int K, int NCOL>
__global__ __launch_bounds__(TPB) void gemm_scale(
    const float* __restrict__ X, const float* __restrict__ W,
    const float* __restrict__ dinv, float* __restrict__ Y, int nrows)
{
    constexpr int CG   = NCOL / 16;
    constexpr int TR   = TPB / CG;
    constexpr int ROWS = TR * 4;
    constexpr int KC   = (K * NCOL <= 8192) ? K : (8192 / NCOL);
    __shared__ float wlds[KC * NCOL];

    const int t    = threadIdx.x;
    const int q    = t % CG;
    const int tr   = t / CG;
    const int row0 = blockIdx.x * ROWS + tr;

    float4 acc[4][4];
#pragma unroll
    for (int i = 0; i < 4; i++)
#pragma unroll
        for (int j = 0; j < 4; j++) acc[i][j] = make_float4(0.f, 0.f, 0.f, 0.f);

    for (int k0 = 0; k0 < K; k0 += KC) {
        __syncthreads();
        for (int i = t; i < KC * NCOL / 4; i += TPB)
            ((float4*)wlds)[i] = ((const float4*)(W + (size_t)k0 * NCOL))[i];
        __syncthreads();

        for (int k = 0; k < KC; k += 4) {
            float4 xv[4];
#pragma unroll
            for (int i = 0; i < 4; i++) {
                int r = row0 + i * TR;
                xv[i] = (r < nrows) ? *(const float4*)(X + (size_t)r * K + k0 + k)
                                    : make_float4(0.f, 0.f, 0.f, 0.f);
            }
#pragma unroll
            for (int kk = 0; kk < 4; kk++) {
                float4 w[4];
#pragma unroll
                for (int j = 0; j < 4; j++)
                    w[j] = *(const float4*)(wlds + (k + kk) * NCOL + q * 16 + j * 4);
#pragma unroll
                for (int i = 0; i < 4; i++) {
                    float xs = (kk == 0) ? xv[i].x : (kk == 1) ? xv[i].y
                             : (kk == 2) ? xv[i].z : xv[i].w;
#pragma unroll
                    for (int j = 0; j < 4; j++) {
                        acc[i][j].x = fmaf(xs, w[j].x, acc[i][j].x);
                        acc[i][j].y = fmaf(xs, w[j].y, acc[i][j].y);
                        acc[i][j].z = fmaf(xs, w[j].z, acc[i][j].z);
                        acc[i][j].w = fmaf(xs, w[j].w, acc[i][j].w);
                    }
                }
            }
        }
    }

#pragma unroll
    for (int i = 0; i < 4; i++) {
        int r = row0 + i * TR;
        if (r < nrows) {
            float dv = dinv[r];
#pragma unroll
            for (int j = 0; j < 4; j++) {
                float4 v = acc[i][j];
                v.x *= dv; v.y *= dv; v.z *= dv; v.w *= dv;
                *(float4*)(Y + (size_t)r * NCOL + q * 16 + j * 4) = v;
            }
        }
    }
}

// ---------------------------------------- pull-mode segment aggregation, fused epilogue
template<int F>
__global__ __launch_bounds__(TPB) void seg_agg(
    const int* __restrict__ off, const int* __restrict__ ssrc,
    const float* __restrict__ y, const float* __restrict__ dinv,
    const float* __restrict__ b, float* __restrict__ H, int n)
{
    constexpr int LOG2F = (F == 64) ? 6 : (F == 32) ? 5 : 4;
    constexpr int NPW   = 64 / F;
    const int lane = threadIdx.x & 63;
    const int f    = lane & (F - 1);
    const int sub  = lane >> LOG2F;
    const int wid  = (blockIdx.x * blockDim.x + threadIdx.x) >> 6;
    const int nw   = (gridDim.x * blockDim.x) >> 6;
    const float bv = b[f];

    for (int v0 = wid * NPW; v0 < n; v0 += nw * NPW) {
        int v = v0 + sub;
        if (v < n) {
            int e0 = off[v], e1 = off[v + 1];
            float s = y[v * F + f];                       // self loop
            for (int base = e0; base < e1; base += F) {
                int idx = (base + f < e1) ? ssrc[base + f] : 0;
                int cnt = min(F, e1 - base);
                for (int j = 0; j < cnt; j++) {
                    int sj = __shfl(idx, sub * F + j, 64);
                    s += y[sj * F + f];
                }
            }
            H[v * F + f] = fmaxf(fmaf(s, dinv[v], bv), 0.f);
        }
    }
}

// layer-3 variant: no H write; fuse mean-pool accumulation (F=16)
__global__ __launch_bounds__(TPB) void seg_agg16_pool(
    const int* __restrict__ off, const int* __restrict__ ssrc,
    const float* __restrict__ y, const float* __restrict__ dinv,
    const float* __restrict__ b, float* __restrict__ pooled, int n)
{
    const int lane = threadIdx.x & 63;
    const int f    = lane & 15;
    const int sub  = lane >> 4;
    const int wid  = (blockIdx.x * blockDim.x + threadIdx.x) >> 6;
    const int nw   = (gridDim.x * blockDim.x) >> 6;
    const float bv = b[f];
    float pacc = 0.f;

    for (int v0 = wid * 4; v0 < n; v0 += nw * 4) {
        int v = v0 + sub;
        if (v < n) {
            int e0 = off[v], e1 = off[v + 1];
            float s = y[v * 16 + f];
            for (int base = e0; base < e1; base += 16) {
                int idx = (base + f < e1) ? ssrc[base + f] : 0;
                int cnt = min(16, e1 - base);
                for (int j = 0; j < cnt; j++) {
                    int sj = __shfl(idx, sub * 16 + j, 64);
                    s += y[sj * 16 + f];
                }
            }
            pacc += fmaxf(fmaf(s, dinv[v], bv), 0.f);
        }
    }
    __shared__ float red[TPB];
    red[threadIdx.x] = pacc; __syncthreads();
    for (int st = 128; st >= 16; st >>= 1) {
        if (threadIdx.x < st) red[threadIdx.x] += red[threadIdx.x + st];
        __syncthreads();
    }
    if (threadIdx.x < 16) atomicAdd(&pooled[threadIdx.x], red[threadIdx.x]);
}

// --------------------------------------------------- tiny MLP head + logsoftmax
__global__ void head_kernel(const float* __restrict__ pooled,
                            const float* __restrict__ Wf, const float* __restrict__ bf,
                            const float* __restrict__ Ws, const float* __restrict__ bs,
                            float* __restrict__ out, float invn)
{
    if (threadIdx.x == 0 && blockIdx.x == 0) {
        float p[16], h[8], s[10];
        for (int i = 0; i < 16; i++) p[i] = pooled[i] * invn;
        for (int j = 0; j < 8; j++) {
            float a = bf[j];
            for (int i = 0; i < 16; i++) a = fmaf(p[i], Wf[i * 8 + j], a);
            h[j] = fmaxf(a, 0.f);
        }
        float m = -1e30f;
        for (int c = 0; c < 10; c++) {
            float a = bs[c];
            for (int j = 0; j < 8; j++) a = fmaf(h[j], Ws[j * 10 + c], a);
            s[c] = a;
            m = fmaxf(m, a);
        }
        float lse = 0.f;
        for (int c = 0; c < 10; c++) lse += expf(s[c] - m);
        lse = logf(lse) + m;
        for (int c = 0; c < 10; c++) out[c] = s[c] - lse;
    }
}

static inline size_t align_up(size_t x) { return (x + 255) & ~(size_t)255; }

extern "C" void kernel_launch(void* const* d_in, const int* in_sizes, int n_in,
                              void* d_out, int out_size, void* d_ws, size_t ws_size,
                              hipStream_t stream)
{
    const float* X  = (const float*)d_in[0];
    const int*   ei = (const int*)  d_in[1];
    const float* W1 = (const float*)d_in[2];  const float* b1 = (const float*)d_in[3];
    const float* W2 = (const float*)d_in[4];  const float* b2 = (const float*)d_in[5];
    const float* W3 = (const float*)d_in[6];  const float* b3 = (const float*)d_in[7];
    const float* Wf = (const float*)d_in[8];  const float* bf = (const float*)d_in[9];
    const float* Ws = (const float*)d_in[10]; const float* bs = (const float*)d_in[11];

    const int n = in_sizes[0] / 256;
    const int E = in_sizes[1] / 2;
    const int* src = ei;
    const int* dst = ei + E;
    const int nbkt = (n + BKT_N - 1) / BKT_N;

    // workspace layout
    char* ws = (char*)d_ws;
    size_t off_b = 0;
    int* bsize   = (int*)(ws + off_b);   off_b += align_up(NB_MAX * 4);
    int* boff    = (int*)(ws + off_b);   off_b += align_up((NB_MAX + 1) * 4);
    int* bcursor = (int*)(ws + off_b);   off_b += align_up(NB_MAX * 4);
    float* dinv  = (float*)(ws + off_b); off_b += align_up((size_t)n * 4);
    int* off     = (int*)(ws + off_b);   off_b += align_up((size_t)(n + 1) * 4);
    float* pooled= (float*)(ws + off_b); off_b += align_up(16 * 4);
    unsigned int* packed = (unsigned int*)(ws + off_b); off_b += align_up((size_t)E * 4);
    int* ssrc    = (int*)(ws + off_b);   off_b += align_up((size_t)E * 4);
    float* Y     = (float*)(ws + off_b); off_b += align_up((size_t)n * 64 * 4);
    float* H     = (float*)(ws + off_b); off_b += align_up((size_t)n * 64 * 4);

    hipMemsetAsync(bsize, 0, NB_MAX * 4, stream);
    hipMemsetAsync(pooled, 0, 16 * 4, stream);

    // graph preprocessing (once; reused by all 3 layers)
    bucket_count<<<1024, TPB, 0, stream>>>(dst, bsize, E, nbkt);
    bucket_scan<<<1, 256, 0, stream>>>(bsize, boff, bcursor, nbkt, E);
    int nchunk = (E + CHUNK - 1) / CHUNK;
    bucket_scatter<<<nchunk, TPB, 0, stream>>>(src, dst, bcursor, packed, E, nbkt);
    bucket_csr<<<nbkt, 256, 0, stream>>>(packed, boff, off, dinv, ssrc, n, nbkt);

    // ---- layer 1: 256 -> 64
    gemm_scale<256, 64><<<(n + 255) / 256, TPB, 0, stream>>>(X, W1, dinv, Y, n);
    seg_agg<64><<<2048, TPB, 0, stream>>>(off, ssrc, Y, dinv, b1, H, n);

    // ---- layer 2: 64 -> 32
    gemm_scale<64, 32><<<(n + 511) / 512, TPB, 0, stream>>>(H, W2, dinv, Y, n);
    seg_agg<32><<<2048, TPB, 0, stream>>>(off, ssrc, Y, dinv, b2, H, n);

    // ---- layer 3: 32 -> 16 (fused pool)
    gemm_scale<32, 16><<<(n + 1023) / 1024, TPB, 0, stream>>>(H, W3, dinv, Y, n);
    seg_agg16_pool<<<1024, TPB, 0, stream>>>(off, ssrc, Y, dinv, b3, pooled, n);

    head_kernel<<<1, 64, 0, stream>>>(pooled, Wf, bf, Ws, bs, (float*)d_out, 1.0f / (float)n);
}

// Round 4
// 388.705 us; speedup vs baseline: 3.8609x; 1.6298x over previous
//
#include <hip/hip_runtime.h>
#include <hip/hip_fp16.h>
#include <math.h>

#define TPB 256
#define BKT_SHIFT 9
#define BKT_N 512              // nodes per bucket
#define NB_MAX 256             // max buckets (n <= 131072)
#define CHUNK 8192             // edges per block-chunk in bucket_scatter

struct __align__(8) Half4 { __half2 a, b; };

// ---------------------------------------------------------------- pass A0: bucket sizes
__global__ __launch_bounds__(TPB) void bucket_count(
    const int* __restrict__ dst, int* __restrict__ bsize, int E, int nbkt)
{
    __shared__ int h[NB_MAX];
    for (int i = threadIdx.x; i < nbkt; i += TPB) h[i] = 0;
    __syncthreads();
    for (int i = blockIdx.x * TPB + threadIdx.x; i < E; i += gridDim.x * TPB)
        atomicAdd(&h[dst[i] >> BKT_SHIFT], 1);
    __syncthreads();
    for (int i = threadIdx.x; i < nbkt; i += TPB)
        if (h[i]) atomicAdd(&bsize[i], h[i]);
}

// ---------------------------------------------------------------- bucket offsets (1 block)
__global__ __launch_bounds__(256) void bucket_scan(
    const int* __restrict__ bsize, int* __restrict__ boff,
    int* __restrict__ bcursor, int nbkt, int E)
{
    int t = threadIdx.x;
    int v = (t < nbkt) ? bsize[t] : 0;
    __shared__ int tmp[256];
    tmp[t] = v; __syncthreads();
    for (int s = 1; s < 256; s <<= 1) {
        int x = (t >= s) ? tmp[t - s] : 0;
        __syncthreads();
        tmp[t] += x;
        __syncthreads();
    }
    if (t < nbkt) { boff[t] = tmp[t] - v; bcursor[t] = tmp[t] - v; }
    if (t == 0) boff[nbkt] = E;
}

// ---------------------------------------------------------------- pass A1: bucketed scatter
// packed edge: (dst_local << 17) | src   (src < 2^17, dst_local < 2^9)
__global__ __launch_bounds__(TPB) void bucket_scatter(
    const int* __restrict__ src, const int* __restrict__ dst,
    int* __restrict__ bcursor, unsigned int* __restrict__ packed, int E, int nbkt)
{
    __shared__ int h[NB_MAX];
    __shared__ int base[NB_MAX];
    for (int c0 = blockIdx.x * CHUNK; c0 < E; c0 += gridDim.x * CHUNK) {
        int c1 = min(c0 + CHUNK, E);
        for (int i = threadIdx.x; i < nbkt; i += TPB) h[i] = 0;
        __syncthreads();
        for (int i = c0 + threadIdx.x; i < c1; i += TPB)
            atomicAdd(&h[dst[i] >> BKT_SHIFT], 1);
        __syncthreads();
        for (int i = threadIdx.x; i < nbkt; i += TPB) {
            int c = h[i];
            base[i] = c ? atomicAdd(&bcursor[i], c) : 0;
            h[i] = 0;
        }
        __syncthreads();
        for (int i = c0 + threadIdx.x; i < c1; i += TPB) {
            int d = dst[i];
            int b = d >> BKT_SHIFT;
            int pos = base[b] + atomicAdd(&h[b], 1);
            packed[pos] = ((unsigned)(d & (BKT_N - 1)) << 17) | (unsigned)src[i];
        }
        __syncthreads();
    }
}

// ---------------------------------------------------------------- pass B: per-bucket CSR
__global__ __launch_bounds__(256) void bucket_csr(
    const unsigned int* __restrict__ packed, const int* __restrict__ boff,
    int* __restrict__ off, float* __restrict__ dinv, int* __restrict__ ssrc,
    int n, int nbkt)
{
    const int b  = blockIdx.x;
    const int e0 = boff[b], e1 = boff[b + 1];
    const int v0 = b << BKT_SHIFT;
    const int nv = min(BKT_N, n - v0);
    const int t  = threadIdx.x;

    __shared__ int hist[BKT_N];
    __shared__ int cur[BKT_N];
    __shared__ int tmp[256];

    for (int i = t; i < nv; i += 256) hist[i] = 0;
    __syncthreads();
    for (int e = e0 + t; e < e1; e += 256)
        atomicAdd(&hist[packed[e] >> 17], 1);
    __syncthreads();

    int a = (2 * t     < nv) ? hist[2 * t]     : 0;
    int c = (2 * t + 1 < nv) ? hist[2 * t + 1] : 0;
    int ps = a + c;
    tmp[t] = ps; __syncthreads();
    for (int s = 1; s < 256; s <<= 1) {
        int x = (t >= s) ? tmp[t - s] : 0;
        __syncthreads();
        tmp[t] += x;
        __syncthreads();
    }
    int ex = tmp[t] - ps;
    if (2 * t < nv) {
        cur[2 * t] = ex;
        off[v0 + 2 * t] = e0 + ex;
        dinv[v0 + 2 * t] = rsqrtf((float)a + 1.0f);
    }
    if (2 * t + 1 < nv) {
        cur[2 * t + 1] = ex + a;
        off[v0 + 2 * t + 1] = e0 + ex + a;
        dinv[v0 + 2 * t + 1] = rsqrtf((float)c + 1.0f);
    }
    if (b == nbkt - 1 && t == 0) off[n] = e1;
    __syncthreads();

    for (int e = e0 + t; e < e1; e += 256) {
        unsigned p = packed[e];
        int dl = p >> 17;
        int s  = p & 0x1FFFF;
        int pos = atomicAdd(&cur[dl], 1);
        ssrc[e0 + pos] = s;
    }
}

// ------------------------------------------------- GEMM: Y = fp16((X@W)*dinv[row])
template<int K, int NCOL>
__global__ __launch_bounds__(TPB) void gemm_scale(
    const float* __restrict__ X, const float* __restrict__ W,
    const float* __restrict__ dinv, __half2* __restrict__ Y, int nrows)
{
    constexpr int CG   = NCOL / 16;
    constexpr int TR   = TPB / CG;
    constexpr int ROWS = TR * 4;
    constexpr int KC   = (K * NCOL <= 8192) ? K : (8192 / NCOL);
    __shared__ float wlds[KC * NCOL];

    const int t    = threadIdx.x;
    const int q    = t % CG;
    const int tr   = t / CG;
    const int row0 = blockIdx.x * ROWS + tr;

    float4 acc[4][4];
#pragma unroll
    for (int i = 0; i < 4; i++)
#pragma unroll
        for (int j = 0; j < 4; j++) acc[i][j] = make_float4(0.f, 0.f, 0.f, 0.f);

    for (int k0 = 0; k0 < K; k0 += KC) {
        __syncthreads();
        for (int i = t; i < KC * NCOL / 4; i += TPB)
            ((float4*)wlds)[i] = ((const float4*)(W + (size_t)k0 * NCOL))[i];
        __syncthreads();

        for (int k = 0; k < KC; k += 4) {
            float4 xv[4];
#pragma unroll
            for (int i = 0; i < 4; i++) {
                int r = row0 + i * TR;
                xv[i] = (r < nrows) ? *(const float4*)(X + (size_t)r * K + k0 + k)
                                    : make_float4(0.f, 0.f, 0.f, 0.f);
            }
#pragma unroll
            for (int kk = 0; kk < 4; kk++) {
                float4 w[4];
#pragma unroll
                for (int j = 0; j < 4; j++)
                    w[j] = *(const float4*)(wlds + (k + kk) * NCOL + q * 16 + j * 4);
#pragma unroll
                for (int i = 0; i < 4; i++) {
                    float xs = (kk == 0) ? xv[i].x : (kk == 1) ? xv[i].y
                             : (kk == 2) ? xv[i].z : xv[i].w;
#pragma unroll
                    for (int j = 0; j < 4; j++) {
                        acc[i][j].x = fmaf(xs, w[j].x, acc[i][j].x);
                        acc[i][j].y = fmaf(xs, w[j].y, acc[i][j].y);
                        acc[i][j].z = fmaf(xs, w[j].z, acc[i][j].z);
                        acc[i][j].w = fmaf(xs, w[j].w, acc[i][j].w);
                    }
                }
            }
        }
    }

#pragma unroll
    for (int i = 0; i < 4; i++) {
        int r = row0 + i * TR;
        if (r < nrows) {
            float dv = dinv[r];
#pragma unroll
            for (int j = 0; j < 4; j++) {
                float4 v = acc[i][j];
                Half4 h4;
                h4.a = __floats2half2_rn(v.x * dv, v.y * dv);
                h4.b = __floats2half2_rn(v.z * dv, v.w * dv);
                *(Half4*)(Y + (size_t)r * (NCOL / 2) + q * 8 + j * 2) = h4;
            }
        }
    }
}

// ---------------------------------------- pull-mode segment aggregation (fp16 gather)
// H[v] = relu(dinv[v]*(sum y[src] + y[v]) + b); L = F/2 lanes per node, half2 loads.
template<int F>
__global__ __launch_bounds__(TPB) void seg_agg_h(
    const int* __restrict__ off, const int* __restrict__ ssrc,
    const __half2* __restrict__ y2, const float* __restrict__ dinv,
    const float* __restrict__ b, float* __restrict__ H, int n)
{
    constexpr int L     = F / 2;
    constexpr int LOG2L = (L == 32) ? 5 : (L == 16) ? 4 : 3;
    constexpr int NPW   = 64 / L;
    const int lane = threadIdx.x & 63;
    const int fl   = lane & (L - 1);
    const int sub  = lane >> LOG2L;
    const int wid  = (blockIdx.x * blockDim.x + threadIdx.x) >> 6;
    const int nw   = (gridDim.x * blockDim.x) >> 6;
    const float2 bv = ((const float2*)b)[fl];

    for (int v0 = wid * NPW; v0 < n; v0 += nw * NPW) {
        int v = v0 + sub;
        if (v >= n) continue;
        int e0 = off[v], e1 = off[v + 1];
        float2 s = __half22float2(y2[(size_t)v * L + fl]);   // self loop
        for (int base = e0; base < e1; base += L) {
            int idx = (base + fl < e1) ? ssrc[base + fl] : 0;
            int cnt = min(L, e1 - base);
            int j = 0;
            for (; j + 4 <= cnt; j += 4) {
                int s0 = __shfl(idx, sub * L + j,     64);
                int s1 = __shfl(idx, sub * L + j + 1, 64);
                int s2 = __shfl(idx, sub * L + j + 2, 64);
                int s3 = __shfl(idx, sub * L + j + 3, 64);
                __half2 h0 = y2[(size_t)s0 * L + fl];
                __half2 h1 = y2[(size_t)s1 * L + fl];
                __half2 h2 = y2[(size_t)s2 * L + fl];
                __half2 h3 = y2[(size_t)s3 * L + fl];
                float2 f0 = __half22float2(h0), f1 = __half22float2(h1);
                float2 f2 = __half22float2(h2), f3 = __half22float2(h3);
                s.x += (f0.x + f1.x) + (f2.x + f3.x);
                s.y += (f0.y + f1.y) + (f2.y + f3.y);
            }
            for (; j < cnt; j++) {
                int sj = __shfl(idx, sub * L + j, 64);
                float2 f0 = __half22float2(y2[(size_t)sj * L + fl]);
                s.x += f0.x; s.y += f0.y;
            }
        }
        float dv = dinv[v];
        float2 r;
        r.x = fmaxf(fmaf(s.x, dv, bv.x), 0.f);
        r.y = fmaxf(fmaf(s.y, dv, bv.y), 0.f);
        ((float2*)H)[(size_t)v * L + fl] = r;
    }
}

// layer-3 variant: F=16 (L=8), fused mean-pool accumulation, no H write
__global__ __launch_bounds__(TPB) void seg_agg16_pool_h(
    const int* __restrict__ off, const int* __restrict__ ssrc,
    const __half2* __restrict__ y2, const float* __restrict__ dinv,
    const float* __restrict__ b, float* __restrict__ pooled, int n)
{
    constexpr int L = 8;
    const int lane = threadIdx.x & 63;
    const int fl   = lane & 7;
    const int sub  = lane >> 3;
    const int wid  = (blockIdx.x * blockDim.x + threadIdx.x) >> 6;
    const int nw   = (gridDim.x * blockDim.x) >> 6;
    const float2 bv = ((const float2*)b)[fl];
    float2 pacc = make_float2(0.f, 0.f);

    for (int v0 = wid * 8; v0 < n; v0 += nw * 8) {
        int v = v0 + sub;
        if (v >= n) continue;
        int e0 = off[v], e1 = off[v + 1];
        float2 s = __half22float2(y2[(size_t)v * L + fl]);
        for (int base = e0; base < e1; base += L) {
            int idx = (base + fl < e1) ? ssrc[base + fl] : 0;
            int cnt = min(L, e1 - base);
            int j = 0;
            for (; j + 4 <= cnt; j += 4) {
                int s0 = __shfl(idx, sub * L + j,     64);
                int s1 = __shfl(idx, sub * L + j + 1, 64);
                int s2 = __shfl(idx, sub * L + j + 2, 64);
                int s3 = __shfl(idx, sub * L + j + 3, 64);
                float2 f0 = __half22float2(y2[(size_t)s0 * L + fl]);
                float2 f1 = __half22float2(y2[(size_t)s1 * L + fl]);
                float2 f2 = __half22float2(y2[(size_t)s2 * L + fl]);
                float2 f3 = __half22float2(y2[(size_t)s3 * L + fl]);
                s.x += (f0.x + f1.x) + (f2.x + f3.x);
                s.y += (f0.y + f1.y) + (f2.y + f3.y);
            }
            for (; j < cnt; j++) {
                int sj = __shfl(idx, sub * L + j, 64);
                float2 f0 = __half22float2(y2[(size_t)sj * L + fl]);
                s.x += f0.x; s.y += f0.y;
            }
        }
        float dv = dinv[v];
        pacc.x += fmaxf(fmaf(s.x, dv, bv.x), 0.f);
        pacc.y += fmaxf(fmaf(s.y, dv, bv.y), 0.f);
    }
    __shared__ float redx[TPB], redy[TPB];
    redx[threadIdx.x] = pacc.x;
    redy[threadIdx.x] = pacc.y;
    __syncthreads();
    for (int st = 128; st >= 8; st >>= 1) {
        if (threadIdx.x < st) {
            redx[threadIdx.x] += redx[threadIdx.x + st];
            redy[threadIdx.x] += redy[threadIdx.x + st];
        }
        __syncthreads();
    }
    if (threadIdx.x < 8) {
        atomicAdd(&pooled[2 * threadIdx.x],     redx[threadIdx.x]);
        atomicAdd(&pooled[2 * threadIdx.x + 1], redy[threadIdx.x]);
    }
}

// --------------------------------------------------- tiny MLP head + logsoftmax
__global__ void head_kernel(const float* __restrict__ pooled,
                            const float* __restrict__ Wf, const float* __restrict__ bf,
                            const float* __restrict__ Ws, const float* __restrict__ bs,
                            float* __restrict__ out, float invn)
{
    if (threadIdx.x == 0 && blockIdx.x == 0) {
        float p[16], h[8], s[10];
        for (int i = 0; i < 16; i++) p[i] = pooled[i] * invn;
        for (int j = 0; j < 8; j++) {
            float a = bf[j];
            for (int i = 0; i < 16; i++) a = fmaf(p[i], Wf[i * 8 + j], a);
            h[j] = fmaxf(a, 0.f);
        }
        float m = -1e30f;
        for (int c = 0; c < 10; c++) {
            float a = bs[c];
            for (int j = 0; j < 8; j++) a = fmaf(h[j], Ws[j * 10 + c], a);
            s[c] = a;
            m = fmaxf(m, a);
        }
        float lse = 0.f;
        for (int c = 0; c < 10; c++) lse += expf(s[c] - m);
        lse = logf(lse) + m;
        for (int c = 0; c < 10; c++) out[c] = s[c] - lse;
    }
}

static inline size_t align_up(size_t x) { return (x + 255) & ~(size_t)255; }

extern "C" void kernel_launch(void* const* d_in, const int* in_sizes, int n_in,
                              void* d_out, int out_size, void* d_ws, size_t ws_size,
                              hipStream_t stream)
{
    const float* X  = (const float*)d_in[0];
    const int*   ei = (const int*)  d_in[1];
    const float* W1 = (const float*)d_in[2];  const float* b1 = (const float*)d_in[3];
    const float* W2 = (const float*)d_in[4];  const float* b2 = (const float*)d_in[5];
    const float* W3 = (const float*)d_in[6];  const float* b3 = (const float*)d_in[7];
    const float* Wf = (const float*)d_in[8];  const float* bf = (const float*)d_in[9];
    const float* Ws = (const float*)d_in[10]; const float* bs = (const float*)d_in[11];

    const int n = in_sizes[0] / 256;
    const int E = in_sizes[1] / 2;
    const int* src = ei;
    const int* dst = ei + E;
    const int nbkt = (n + BKT_N - 1) / BKT_N;

    // workspace layout
    char* ws = (char*)d_ws;
    size_t off_b = 0;
    int* bsize   = (int*)(ws + off_b);   off_b += align_up(NB_MAX * 4);
    int* boff    = (int*)(ws + off_b);   off_b += align_up((NB_MAX + 1) * 4);
    int* bcursor = (int*)(ws + off_b);   off_b += align_up(NB_MAX * 4);
    float* dinv  = (float*)(ws + off_b); off_b += align_up((size_t)n * 4);
    int* off     = (int*)(ws + off_b);   off_b += align_up((size_t)(n + 1) * 4);
    float* pooled= (float*)(ws + off_b); off_b += align_up(16 * 4);
    unsigned int* packed = (unsigned int*)(ws + off_b); off_b += align_up((size_t)E * 4);
    int* ssrc    = (int*)(ws + off_b);   off_b += align_up((size_t)E * 4);
    __half2* Y   = (__half2*)(ws + off_b); off_b += align_up((size_t)n * 64 * 2);
    float* H     = (float*)(ws + off_b); off_b += align_up((size_t)n * 64 * 4);

    hipMemsetAsync(bsize, 0, NB_MAX * 4, stream);
    hipMemsetAsync(pooled, 0, 16 * 4, stream);

    // graph preprocessing (once; reused by all 3 layers)
    bucket_count<<<1024, TPB, 0, stream>>>(dst, bsize, E, nbkt);
    bucket_scan<<<1, 256, 0, stream>>>(bsize, boff, bcursor, nbkt, E);
    int nchunk = (E + CHUNK - 1) / CHUNK;
    bucket_scatter<<<nchunk, TPB, 0, stream>>>(src, dst, bcursor, packed, E, nbkt);
    bucket_csr<<<nbkt, 256, 0, stream>>>(packed, boff, off, dinv, ssrc, n, nbkt);

    // ---- layer 1: 256 -> 64
    gemm_scale<256, 64><<<(n + 255) / 256, TPB, 0, stream>>>(X, W1, dinv, Y, n);
    seg_agg_h<64><<<2048, TPB, 0, stream>>>(off, ssrc, Y, dinv, b1, H, n);

    // ---- layer 2: 64 -> 32
    gemm_scale<64, 32><<<(n + 511) / 512, TPB, 0, stream>>>(H, W2, dinv, Y, n);
    seg_agg_h<32><<<2048, TPB, 0, stream>>>(off, ssrc, Y, dinv, b2, H, n);

    // ---- layer 3: 32 -> 16 (fused pool)
    gemm_scale<32, 16><<<(n + 1023) / 1024, TPB, 0, stream>>>(H, W3, dinv, Y, n);
    seg_agg16_pool_h<<<1024, TPB, 0, stream>>>(off, ssrc, Y, dinv, b3, pooled, n);

    head_kernel<<<1, 64, 0, stream>>>(pooled, Wf, bf, Ws, bs, (float*)d_out, 1.0f / (float)n);
}

// Round 5
// 327.762 us; speedup vs baseline: 4.5788x; 1.1859x over previous
//
#include <hip/hip_runtime.h>
#include <hip/hip_fp16.h>
#include <math.h>

#define TPB 256
#define BKT_SHIFT 9
#define BKT_N 512              // nodes per bucket
#define NB_MAX 256             // max buckets (n <= 131072)
#define CHUNK 8192             // edges per block-chunk in bucket_scatter

typedef short bf16x8 __attribute__((ext_vector_type(8)));
typedef float f32x4  __attribute__((ext_vector_type(4)));

static __device__ inline unsigned short f2bf(float f) {
    union { float f; unsigned u; } v; v.f = f;
    unsigned r = v.u + 0x7FFF + ((v.u >> 16) & 1);
    return (unsigned short)(r >> 16);
}

// ---------------------------------------------------------------- pass A0: bucket sizes
__global__ __launch_bounds__(TPB) void bucket_count(
    const int* __restrict__ dst, int* __restrict__ bsize, int E, int nbkt)
{
    __shared__ int h[NB_MAX];
    for (int i = threadIdx.x; i < nbkt; i += TPB) h[i] = 0;
    __syncthreads();
    for (int i = blockIdx.x * TPB + threadIdx.x; i < E; i += gridDim.x * TPB)
        atomicAdd(&h[dst[i] >> BKT_SHIFT], 1);
    __syncthreads();
    for (int i = threadIdx.x; i < nbkt; i += TPB)
        if (h[i]) atomicAdd(&bsize[i], h[i]);
}

// ---------------------------------------------------------------- bucket offsets (1 block)
__global__ __launch_bounds__(256) void bucket_scan(
    const int* __restrict__ bsize, int* __restrict__ boff,
    int* __restrict__ bcursor, int nbkt, int E)
{
    int t = threadIdx.x;
    int v = (t < nbkt) ? bsize[t] : 0;
    __shared__ int tmp[256];
    tmp[t] = v; __syncthreads();
    for (int s = 1; s < 256; s <<= 1) {
        int x = (t >= s) ? tmp[t - s] : 0;
        __syncthreads();
        tmp[t] += x;
        __syncthreads();
    }
    if (t < nbkt) { boff[t] = tmp[t] - v; bcursor[t] = tmp[t] - v; }
    if (t == 0) boff[nbkt] = E;
}

// ---------------------------------------------------------------- pass A1: bucketed scatter
__global__ __launch_bounds__(TPB) void bucket_scatter(
    const int* __restrict__ src, const int* __restrict__ dst,
    int* __restrict__ bcursor, unsigned int* __restrict__ packed, int E, int nbkt)
{
    __shared__ int h[NB_MAX];
    __shared__ int base[NB_MAX];
    for (int c0 = blockIdx.x * CHUNK; c0 < E; c0 += gridDim.x * CHUNK) {
        int c1 = min(c0 + CHUNK, E);
        for (int i = threadIdx.x; i < nbkt; i += TPB) h[i] = 0;
        __syncthreads();
        for (int i = c0 + threadIdx.x; i < c1; i += TPB)
            atomicAdd(&h[dst[i] >> BKT_SHIFT], 1);
        __syncthreads();
        for (int i = threadIdx.x; i < nbkt; i += TPB) {
            int c = h[i];
            base[i] = c ? atomicAdd(&bcursor[i], c) : 0;
            h[i] = 0;
        }
        __syncthreads();
        for (int i = c0 + threadIdx.x; i < c1; i += TPB) {
            int d = dst[i];
            int b = d >> BKT_SHIFT;
            int pos = base[b] + atomicAdd(&h[b], 1);
            packed[pos] = ((unsigned)(d & (BKT_N - 1)) << 17) | (unsigned)src[i];
        }
        __syncthreads();
    }
}

// ---------------------------------------------------------------- pass B: per-bucket CSR
__global__ __launch_bounds__(256) void bucket_csr(
    const unsigned int* __restrict__ packed, const int* __restrict__ boff,
    int* __restrict__ off, float* __restrict__ dinv, int* __restrict__ ssrc,
    int n, int nbkt)
{
    const int b  = blockIdx.x;
    const int e0 = boff[b], e1 = boff[b + 1];
    const int v0 = b << BKT_SHIFT;
    const int nv = min(BKT_N, n - v0);
    const int t  = threadIdx.x;

    __shared__ int hist[BKT_N];
    __shared__ int cur[BKT_N];
    __shared__ int tmp[256];

    for (int i = t; i < nv; i += 256) hist[i] = 0;
    __syncthreads();
    for (int e = e0 + t; e < e1; e += 256)
        atomicAdd(&hist[packed[e] >> 17], 1);
    __syncthreads();

    int a = (2 * t     < nv) ? hist[2 * t]     : 0;
    int c = (2 * t + 1 < nv) ? hist[2 * t + 1] : 0;
    int ps = a + c;
    tmp[t] = ps; __syncthreads();
    for (int s = 1; s < 256; s <<= 1) {
        int x = (t >= s) ? tmp[t - s] : 0;
        __syncthreads();
        tmp[t] += x;
        __syncthreads();
    }
    int ex = tmp[t] - ps;
    if (2 * t < nv) {
        cur[2 * t] = ex;
        off[v0 + 2 * t] = e0 + ex;
        dinv[v0 + 2 * t] = rsqrtf((float)a + 1.0f);
    }
    if (2 * t + 1 < nv) {
        cur[2 * t + 1] = ex + a;
        off[v0 + 2 * t + 1] = e0 + ex + a;
        dinv[v0 + 2 * t + 1] = rsqrtf((float)c + 1.0f);
    }
    if (b == nbkt - 1 && t == 0) off[n] = e1;
    __syncthreads();

    for (int e = e0 + t; e < e1; e += 256) {
        unsigned p = packed[e];
        int dl = p >> 17;
        int s  = p & 0x1FFFF;
        int pos = atomicAdd(&cur[dl], 1);
        ssrc[e0 + pos] = s;
    }
}

// ---------------------------------------------------------------- W -> bf16 transposed
// Wt[c*K + k] = bf16(W[k*N + c])
__global__ __launch_bounds__(256) void conv_w(
    const float* __restrict__ W, unsigned short* __restrict__ Wt, int K, int N)
{
    int total = K * N;
    for (int i = threadIdx.x + blockIdx.x * 256; i < total; i += gridDim.x * 256) {
        int k = i / N, c = i % N;
        Wt[c * K + k] = f2bf(W[i]);
    }
}

// ---------------------------------------------------------------- MFMA GEMM
// Y = fp16((A@W)*dinv[row]).  A: fp32 (layer1, converted in-reg) or bf16 (H).
// Block = 128 rows x NCOL, 4 waves; wave = 32 rows (2 M-tiles) x NCOL.
// Wt is bf16 [NCOL][K] (transposed), L2-resident; B frags loaded直接 from global.
template<int K, int NCOL, typename AT>
__global__ __launch_bounds__(TPB) void gemm_mfma(
    const AT* __restrict__ A, const unsigned short* __restrict__ Wt,
    const float* __restrict__ dinv, __half* __restrict__ Y, int n)
{
    constexpr int NT = NCOL / 16;
    constexpr int KS = K / 32;
    const int lane = threadIdx.x & 63;
    const int w    = threadIdx.x >> 6;
    const int rowbase = blockIdx.x * 128 + w * 32;
    const int arow = lane & 15;
    const int kb   = (lane >> 4) * 8;

    f32x4 acc[2][NT];
#pragma unroll
    for (int mt = 0; mt < 2; mt++)
#pragma unroll
        for (int nt = 0; nt < NT; nt++) acc[mt][nt] = (f32x4)(0.f);

#pragma unroll
    for (int ks = 0; ks < KS; ks++) {
        bf16x8 a[2];
#pragma unroll
        for (int mt = 0; mt < 2; mt++) {
            int r = rowbase + mt * 16 + arow;
            if constexpr (sizeof(AT) == 4) {
                if (r < n) {
                    const float4* p = (const float4*)(A + (size_t)r * K + ks * 32 + kb);
                    float4 u = p[0], v = p[1];
                    a[mt][0] = f2bf(u.x); a[mt][1] = f2bf(u.y);
                    a[mt][2] = f2bf(u.z); a[mt][3] = f2bf(u.w);
                    a[mt][4] = f2bf(v.x); a[mt][5] = f2bf(v.y);
                    a[mt][6] = f2bf(v.z); a[mt][7] = f2bf(v.w);
                } else {
#pragma unroll
                    for (int i = 0; i < 8; i++) a[mt][i] = 0;
                }
            } else {
                if (r < n)
                    a[mt] = *(const bf16x8*)(A + (size_t)r * K + ks * 32 + kb);
                else {
#pragma unroll
                    for (int i = 0; i < 8; i++) a[mt][i] = 0;
                }
            }
        }
        bf16x8 b[NT];
#pragma unroll
        for (int nt = 0; nt < NT; nt++)
            b[nt] = *(const bf16x8*)(Wt + (size_t)(nt * 16 + arow) * K + ks * 32 + kb);
#pragma unroll
        for (int mt = 0; mt < 2; mt++)
#pragma unroll
            for (int nt = 0; nt < NT; nt++)
                acc[mt][nt] = __builtin_amdgcn_mfma_f32_16x16x32_bf16(
                    a[mt], b[nt], acc[mt][nt], 0, 0, 0);
    }

#pragma unroll
    for (int mt = 0; mt < 2; mt++) {
        int r0 = rowbase + mt * 16 + (lane >> 4) * 4;
#pragma unroll
        for (int j = 0; j < 4; j++) {
            int r = r0 + j;
            if (r < n) {
                float dv = dinv[r];
#pragma unroll
                for (int nt = 0; nt < NT; nt++)
                    Y[(size_t)r * NCOL + nt * 16 + arow] = __float2half(acc[mt][nt][j] * dv);
            }
        }
    }
}

// ---------------------------------------- pull-mode segment aggregation (fp16 gather)
// H[v] = relu(dinv[v]*(sum y[src] + y[v]) + b), written as packed bf16x2.
template<int F>
__global__ __launch_bounds__(TPB) void seg_agg_h(
    const int* __restrict__ off, const int* __restrict__ ssrc,
    const __half2* __restrict__ y2, const float* __restrict__ dinv,
    const float* __restrict__ b, unsigned int* __restrict__ H, int n)
{
    constexpr int L     = F / 2;
    constexpr int LOG2L = (L == 32) ? 5 : (L == 16) ? 4 : 3;
    constexpr int NPW   = 64 / L;
    const int lane = threadIdx.x & 63;
    const int fl   = lane & (L - 1);
    const int sub  = lane >> LOG2L;
    const int wid  = (blockIdx.x * blockDim.x + threadIdx.x) >> 6;
    const int nw   = (gridDim.x * blockDim.x) >> 6;
    const float2 bv = ((const float2*)b)[fl];

    for (int v0 = wid * NPW; v0 < n; v0 += nw * NPW) {
        int v = v0 + sub;
        if (v >= n) continue;
        int e0 = off[v], e1 = off[v + 1];
        float2 s = __half22float2(y2[(size_t)v * L + fl]);   // self loop
        for (int base = e0; base < e1; base += L) {
            int idx = (base + fl < e1) ? ssrc[base + fl] : 0;
            int cnt = min(L, e1 - base);
            int j = 0;
            for (; j + 4 <= cnt; j += 4) {
                int s0 = __shfl(idx, sub * L + j,     64);
                int s1 = __shfl(idx, sub * L + j + 1, 64);
                int s2 = __shfl(idx, sub * L + j + 2, 64);
                int s3 = __shfl(idx, sub * L + j + 3, 64);
                float2 f0 = __half22float2(y2[(size_t)s0 * L + fl]);
                float2 f1 = __half22float2(y2[(size_t)s1 * L + fl]);
                float2 f2 = __half22float2(y2[(size_t)s2 * L + fl]);
                float2 f3 = __half22float2(y2[(size_t)s3 * L + fl]);
                s.x += (f0.x + f1.x) + (f2.x + f3.x);
                s.y += (f0.y + f1.y) + (f2.y + f3.y);
            }
            for (; j < cnt; j++) {
                int sj = __shfl(idx, sub * L + j, 64);
                float2 f0 = __half22float2(y2[(size_t)sj * L + fl]);
                s.x += f0.x; s.y += f0.y;
            }
        }
        float dv = dinv[v];
        float rx = fmaxf(fmaf(s.x, dv, bv.x), 0.f);
        float ry = fmaxf(fmaf(s.y, dv, bv.y), 0.f);
        H[(size_t)v * L + fl] = ((unsigned)f2bf(ry) << 16) | (unsigned)f2bf(rx);
    }
}

// layer-3 variant: F=16 (L=8), fused mean-pool accumulation, no H write
__global__ __launch_bounds__(TPB) void seg_agg16_pool_h(
    const int* __restrict__ off, const int* __restrict__ ssrc,
    const __half2* __restrict__ y2, const float* __restrict__ dinv,
    const float* __restrict__ b, float* __restrict__ pooled, int n)
{
    constexpr int L = 8;
    const int lane = threadIdx.x & 63;
    const int fl   = lane & 7;
    const int sub  = lane >> 3;
    const int wid  = (blockIdx.x * blockDim.x + threadIdx.x) >> 6;
    const int nw   = (gridDim.x * blockDim.x) >> 6;
    const float2 bv = ((const float2*)b)[fl];
    float2 pacc = make_float2(0.f, 0.f);

    for (int v0 = wid * 8; v0 < n; v0 += nw * 8) {
        int v = v0 + sub;
        if (v >= n) continue;
        int e0 = off[v], e1 = off[v + 1];
        float2 s = __half22float2(y2[(size_t)v * L + fl]);
        for (int base = e0; base < e1; base += L) {
            int idx = (base + fl < e1) ? ssrc[base + fl] : 0;
            int cnt = min(L, e1 - base);
            int j = 0;
            for (; j + 4 <= cnt; j += 4) {
                int s0 = __shfl(idx, sub * L + j,     64);
                int s1 = __shfl(idx, sub * L + j + 1, 64);
                int s2 = __shfl(idx, sub * L + j + 2, 64);
                int s3 = __shfl(idx, sub * L + j + 3, 64);
                float2 f0 = __half22float2(y2[(size_t)s0 * L + fl]);
                float2 f1 = __half22float2(y2[(size_t)s1 * L + fl]);
                float2 f2 = __half22float2(y2[(size_t)s2 * L + fl]);
                float2 f3 = __half22float2(y2[(size_t)s3 * L + fl]);
                s.x += (f0.x + f1.x) + (f2.x + f3.x);
                s.y += (f0.y + f1.y) + (f2.y + f3.y);
            }
            for (; j < cnt; j++) {
                int sj = __shfl(idx, sub * L + j, 64);
                float2 f0 = __half22float2(y2[(size_t)sj * L + fl]);
                s.x += f0.x; s.y += f0.y;
            }
        }
        float dv = dinv[v];
        pacc.x += fmaxf(fmaf(s.x, dv, bv.x), 0.f);
        pacc.y += fmaxf(fmaf(s.y, dv, bv.y), 0.f);
    }
    __shared__ float redx[TPB], redy[TPB];
    redx[threadIdx.x] = pacc.x;
    redy[threadIdx.x] = pacc.y;
    __syncthreads();
    for (int st = 128; st >= 8; st >>= 1) {
        if (threadIdx.x < st) {
            redx[threadIdx.x] += redx[threadIdx.x + st];
            redy[threadIdx.x] += redy[threadIdx.x + st];
        }
        __syncthreads();
    }
    if (threadIdx.x < 8) {
        atomicAdd(&pooled[2 * threadIdx.x],     redx[threadIdx.x]);
        atomicAdd(&pooled[2 * threadIdx.x + 1], redy[threadIdx.x]);
    }
}

// --------------------------------------------------- tiny MLP head + logsoftmax
__global__ void head_kernel(const float* __restrict__ pooled,
                            const float* __restrict__ Wf, const float* __restrict__ bf,
                            const float* __restrict__ Ws, const float* __restrict__ bs,
                            float* __restrict__ out, float invn)
{
    if (threadIdx.x == 0 && blockIdx.x == 0) {
        float p[16], h[8], s[10];
        for (int i = 0; i < 16; i++) p[i] = pooled[i] * invn;
        for (int j = 0; j < 8; j++) {
            float a = bf[j];
            for (int i = 0; i < 16; i++) a = fmaf(p[i], Wf[i * 8 + j], a);
            h[j] = fmaxf(a, 0.f);
        }
        float m = -1e30f;
        for (int c = 0; c < 10; c++) {
            float a = bs[c];
            for (int j = 0; j < 8; j++) a = fmaf(h[j], Ws[j * 10 + c], a);
            s[c] = a;
            m = fmaxf(m, a);
        }
        float lse = 0.f;
        for (int c = 0; c < 10; c++) lse += expf(s[c] - m);
        lse = logf(lse) + m;
        for (int c = 0; c < 10; c++) out[c] = s[c] - lse;
    }
}

static inline size_t align_up(size_t x) { return (x + 255) & ~(size_t)255; }

extern "C" void kernel_launch(void* const* d_in, const int* in_sizes, int n_in,
                              void* d_out, int out_size, void* d_ws, size_t ws_size,
                              hipStream_t stream)
{
    const float* X  = (const float*)d_in[0];
    const int*   ei = (const int*)  d_in[1];
    const float* W1 = (const float*)d_in[2];  const float* b1 = (const float*)d_in[3];
    const float* W2 = (const float*)d_in[4];  const float* b2 = (const float*)d_in[5];
    const float* W3 = (const float*)d_in[6];  const float* b3 = (const float*)d_in[7];
    const float* Wf = (const float*)d_in[8];  const float* bf = (const float*)d_in[9];
    const float* Ws = (const float*)d_in[10]; const float* bs = (const float*)d_in[11];

    const int n = in_sizes[0] / 256;
    const int E = in_sizes[1] / 2;
    const int* src = ei;
    const int* dst = ei + E;
    const int nbkt = (n + BKT_N - 1) / BKT_N;

    // workspace layout
    char* ws = (char*)d_ws;
    size_t off_b = 0;
    int* bsize   = (int*)(ws + off_b);   off_b += align_up(NB_MAX * 4);
    int* boff    = (int*)(ws + off_b);   off_b += align_up((NB_MAX + 1) * 4);
    int* bcursor = (int*)(ws + off_b);   off_b += align_up(NB_MAX * 4);
    float* dinv  = (float*)(ws + off_b); off_b += align_up((size_t)n * 4);
    int* off     = (int*)(ws + off_b);   off_b += align_up((size_t)(n + 1) * 4);
    float* pooled= (float*)(ws + off_b); off_b += align_up(16 * 4);
    unsigned short* Wt1 = (unsigned short*)(ws + off_b); off_b += align_up(64 * 256 * 2);
    unsigned short* Wt2 = (unsigned short*)(ws + off_b); off_b += align_up(32 * 64 * 2);
    unsigned short* Wt3 = (unsigned short*)(ws + off_b); off_b += align_up(16 * 32 * 2);
    unsigned int* packed = (unsigned int*)(ws + off_b); off_b += align_up((size_t)E * 4);
    int* ssrc    = (int*)(ws + off_b);   off_b += align_up((size_t)E * 4);
    __half2* Y   = (__half2*)(ws + off_b); off_b += align_up((size_t)n * 64 * 2);
    unsigned int* H = (unsigned int*)(ws + off_b); off_b += align_up((size_t)n * 64 * 2);

    hipMemsetAsync(bsize, 0, NB_MAX * 4, stream);
    hipMemsetAsync(pooled, 0, 16 * 4, stream);

    // graph preprocessing (once; reused by all 3 layers)
    bucket_count<<<1024, TPB, 0, stream>>>(dst, bsize, E, nbkt);
    bucket_scan<<<1, 256, 0, stream>>>(bsize, boff, bcursor, nbkt, E);
    int nchunk = (E + CHUNK - 1) / CHUNK;
    bucket_scatter<<<nchunk, TPB, 0, stream>>>(src, dst, bcursor, packed, E, nbkt);
    bucket_csr<<<nbkt, 256, 0, stream>>>(packed, boff, off, dinv, ssrc, n, nbkt);

    // weight conversion (bf16, transposed)
    conv_w<<<16, 256, 0, stream>>>(W1, Wt1, 256, 64);
    conv_w<<<2, 256, 0, stream>>>(W2, Wt2, 64, 32);
    conv_w<<<1, 256, 0, stream>>>(W3, Wt3, 32, 16);

    const int gblk = (n + 127) / 128;

    // ---- layer 1: 256 -> 64
    gemm_mfma<256, 64, float><<<gblk, TPB, 0, stream>>>(X, Wt1, dinv, (__half*)Y, n);
    seg_agg_h<64><<<2048, TPB, 0, stream>>>(off, ssrc, Y, dinv, b1, H, n);

    // ---- layer 2: 64 -> 32
    gemm_mfma<64, 32, unsigned short><<<gblk, TPB, 0, stream>>>(
        (const unsigned short*)H, Wt2, dinv, (__half*)Y, n);
    seg_agg_h<32><<<2048, TPB, 0, stream>>>(off, ssrc, Y, dinv, b2, H, n);

    // ---- layer 3: 32 -> 16 (fused pool)
    gemm_mfma<32, 16, unsigned short><<<gblk, TPB, 0, stream>>>(
        (const unsigned short*)H, Wt3, dinv, (__half*)Y, n);
    seg_agg16_pool_h<<<1024, TPB, 0, stream>>>(off, ssrc, Y, dinv, b3, pooled, n);

    head_kernel<<<1, 64, 0, stream>>>(pooled, Wf, bf, Ws, bs, (float*)d_out, 1.0f / (float)n);
}

// Round 6
// 301.057 us; speedup vs baseline: 4.9850x; 1.0887x over previous
//
#include <hip/hip_runtime.h>
#include <hip/hip_fp16.h>
#include <math.h>

#define TPB 256
#define BKT_SHIFT 9
#define BKT_N 512              // nodes per bucket
#define NB_MAX 256             // max buckets (n <= 131072)
#define CHUNK 4096             // edges per block-chunk in bucket_scatter
#define CAP   24576            // padded packed-region capacity per bucket

typedef short bf16x8 __attribute__((ext_vector_type(8)));
typedef float f32x4  __attribute__((ext_vector_type(4)));

static __device__ inline unsigned short f2bf(float f) {
    union { float f; unsigned u; } v; v.f = f;
    unsigned r = v.u + 0x7FFF + ((v.u >> 16) & 1);
    return (unsigned short)(r >> 16);
}

// ---------------------------------------------------------------- cursor init
__global__ __launch_bounds__(256) void init_cursor(int* __restrict__ bcursor, int nbkt) {
    int t = threadIdx.x;
    if (t < nbkt) bcursor[t] = t * CAP;
}

// ---------------------------------------------------------------- bucketed scatter
// Single global read pass; (packed, bucket) staged in LDS; padded regions.
// packed edge: (dst_local << 17) | src   (src < 2^17, dst_local < 2^9)
__global__ __launch_bounds__(TPB) void bucket_scatter(
    const int* __restrict__ src, const int* __restrict__ dst,
    int* __restrict__ bcursor, unsigned int* __restrict__ packed, int E, int nbkt)
{
    __shared__ unsigned int  spk[CHUNK];
    __shared__ unsigned char sbk[CHUNK];
    __shared__ int h[NB_MAX];
    __shared__ int base[NB_MAX];
    for (int c0 = blockIdx.x * CHUNK; c0 < E; c0 += gridDim.x * CHUNK) {
        int m = min(CHUNK, E - c0);
        for (int i = threadIdx.x; i < nbkt; i += TPB) h[i] = 0;
        __syncthreads();
        for (int i = threadIdx.x; i < m; i += TPB) {
            int d = dst[c0 + i];
            int s = src[c0 + i];
            int b = d >> BKT_SHIFT;
            spk[i] = ((unsigned)(d & (BKT_N - 1)) << 17) | (unsigned)s;
            sbk[i] = (unsigned char)b;
            atomicAdd(&h[b], 1);
        }
        __syncthreads();
        for (int i = threadIdx.x; i < nbkt; i += TPB) {
            int c = h[i];
            base[i] = c ? atomicAdd(&bcursor[i], c) : 0;
            h[i] = 0;
        }
        __syncthreads();
        for (int i = threadIdx.x; i < m; i += TPB) {
            int b = sbk[i];
            int pos = base[b] + atomicAdd(&h[b], 1);
            packed[pos] = spk[i];
        }
        __syncthreads();
    }
}

// ---------------------------------------------------------------- bucket offsets (1 block)
// cnt[b] = bcursor[b] - b*CAP; boff = exclusive scan
__global__ __launch_bounds__(256) void bucket_offsets(
    const int* __restrict__ bcursor, int* __restrict__ boff, int nbkt, int E)
{
    int t = threadIdx.x;
    int v = (t < nbkt) ? (bcursor[t] - t * CAP) : 0;
    __shared__ int tmp[256];
    tmp[t] = v; __syncthreads();
    for (int s = 1; s < 256; s <<= 1) {
        int x = (t >= s) ? tmp[t - s] : 0;
        __syncthreads();
        tmp[t] += x;
        __syncthreads();
    }
    if (t < nbkt) boff[t] = tmp[t] - v;
    if (t == 0) boff[nbkt] = E;
}

// ---------------------------------------------------------------- per-bucket CSR
// packed region: [b*CAP, b*CAP+cnt); dense ssrc at boff[b]
__global__ __launch_bounds__(256) void bucket_csr(
    const unsigned int* __restrict__ packed, const int* __restrict__ boff,
    int* __restrict__ off, float* __restrict__ dinv, int* __restrict__ ssrc,
    int n, int nbkt)
{
    const int b   = blockIdx.x;
    const int e0  = boff[b];
    const int cnt = boff[b + 1] - e0;
    const int p0  = b * CAP;
    const int v0  = b << BKT_SHIFT;
    const int nv  = min(BKT_N, n - v0);
    const int t   = threadIdx.x;

    __shared__ int hist[BKT_N];
    __shared__ int cur[BKT_N];
    __shared__ int tmp[256];

    for (int i = t; i < nv; i += 256) hist[i] = 0;
    __syncthreads();
    for (int e = t; e < cnt; e += 256)
        atomicAdd(&hist[packed[p0 + e] >> 17], 1);
    __syncthreads();

    int a = (2 * t     < nv) ? hist[2 * t]     : 0;
    int c = (2 * t + 1 < nv) ? hist[2 * t + 1] : 0;
    int ps = a + c;
    tmp[t] = ps; __syncthreads();
    for (int s = 1; s < 256; s <<= 1) {
        int x = (t >= s) ? tmp[t - s] : 0;
        __syncthreads();
        tmp[t] += x;
        __syncthreads();
    }
    int ex = tmp[t] - ps;
    if (2 * t < nv) {
        cur[2 * t] = ex;
        off[v0 + 2 * t] = e0 + ex;
        dinv[v0 + 2 * t] = rsqrtf((float)a + 1.0f);
    }
    if (2 * t + 1 < nv) {
        cur[2 * t + 1] = ex + a;
        off[v0 + 2 * t + 1] = e0 + ex + a;
        dinv[v0 + 2 * t + 1] = rsqrtf((float)c + 1.0f);
    }
    if (b == nbkt - 1 && t == 0) off[n] = boff[nbkt];
    __syncthreads();

    for (int e = t; e < cnt; e += 256) {
        unsigned p = packed[p0 + e];
        int dl = p >> 17;
        int s  = p & 0x1FFFF;
        int pos = atomicAdd(&cur[dl], 1);
        ssrc[e0 + pos] = s;
    }
}

// ---------------------------------------------------------------- W -> bf16 transposed
__global__ __launch_bounds__(256) void conv_w(
    const float* __restrict__ W, unsigned short* __restrict__ Wt, int K, int N)
{
    int total = K * N;
    for (int i = threadIdx.x + blockIdx.x * 256; i < total; i += gridDim.x * 256) {
        int k = i / N, c = i % N;
        Wt[c * K + k] = f2bf(W[i]);
    }
}

// ---------------------------------------------------------------- MFMA GEMM
// Y = fp16((A@W)*dinv[row]).  A: fp32 (layer1) or bf16 (H).
template<int K, int NCOL, typename AT>
__global__ __launch_bounds__(TPB) void gemm_mfma(
    const AT* __restrict__ A, const unsigned short* __restrict__ Wt,
    const float* __restrict__ dinv, __half* __restrict__ Y, int n)
{
    constexpr int NT = NCOL / 16;
    constexpr int KS = K / 32;
    const int lane = threadIdx.x & 63;
    const int w    = threadIdx.x >> 6;
    const int rowbase = blockIdx.x * 128 + w * 32;
    const int arow = lane & 15;
    const int kb   = (lane >> 4) * 8;

    f32x4 acc[2][NT];
#pragma unroll
    for (int mt = 0; mt < 2; mt++)
#pragma unroll
        for (int nt = 0; nt < NT; nt++) acc[mt][nt] = (f32x4)(0.f);

#pragma unroll
    for (int ks = 0; ks < KS; ks++) {
        bf16x8 a[2];
#pragma unroll
        for (int mt = 0; mt < 2; mt++) {
            int r = rowbase + mt * 16 + arow;
            if constexpr (sizeof(AT) == 4) {
                if (r < n) {
                    const float4* p = (const float4*)(A + (size_t)r * K + ks * 32 + kb);
                    float4 u = p[0], v = p[1];
                    a[mt][0] = f2bf(u.x); a[mt][1] = f2bf(u.y);
                    a[mt][2] = f2bf(u.z); a[mt][3] = f2bf(u.w);
                    a[mt][4] = f2bf(v.x); a[mt][5] = f2bf(v.y);
                    a[mt][6] = f2bf(v.z); a[mt][7] = f2bf(v.w);
                } else {
#pragma unroll
                    for (int i = 0; i < 8; i++) a[mt][i] = 0;
                }
            } else {
                if (r < n)
                    a[mt] = *(const bf16x8*)(A + (size_t)r * K + ks * 32 + kb);
                else {
#pragma unroll
                    for (int i = 0; i < 8; i++) a[mt][i] = 0;
                }
            }
        }
        bf16x8 b[NT];
#pragma unroll
        for (int nt = 0; nt < NT; nt++)
            b[nt] = *(const bf16x8*)(Wt + (size_t)(nt * 16 + arow) * K + ks * 32 + kb);
#pragma unroll
        for (int mt = 0; mt < 2; mt++)
#pragma unroll
            for (int nt = 0; nt < NT; nt++)
                acc[mt][nt] = __builtin_amdgcn_mfma_f32_16x16x32_bf16(
                    a[mt], b[nt], acc[mt][nt], 0, 0, 0);
    }

#pragma unroll
    for (int mt = 0; mt < 2; mt++) {
        int r0 = rowbase + mt * 16 + (lane >> 4) * 4;
#pragma unroll
        for (int j = 0; j < 4; j++) {
            int r = r0 + j;
            if (r < n) {
                float dv = dinv[r];
#pragma unroll
                for (int nt = 0; nt < NT; nt++)
                    Y[(size_t)r * NCOL + nt * 16 + arow] = __float2half(acc[mt][nt][j] * dv);
            }
        }
    }
}

// ---------------------------------------- pull-mode segment aggregation (fp16 gather)
template<int F>
__global__ __launch_bounds__(TPB) void seg_agg_h(
    const int* __restrict__ off, const int* __restrict__ ssrc,
    const __half2* __restrict__ y2, const float* __restrict__ dinv,
    const float* __restrict__ b, unsigned int* __restrict__ H, int n)
{
    constexpr int L     = F / 2;
    constexpr int LOG2L = (L == 32) ? 5 : (L == 16) ? 4 : 3;
    constexpr int NPW   = 64 / L;
    const int lane = threadIdx.x & 63;
    const int fl   = lane & (L - 1);
    const int sub  = lane >> LOG2L;
    const int wid  = (blockIdx.x * blockDim.x + threadIdx.x) >> 6;
    const int nw   = (gridDim.x * blockDim.x) >> 6;
    const float2 bv = ((const float2*)b)[fl];

    for (int v0 = wid * NPW; v0 < n; v0 += nw * NPW) {
        int v = v0 + sub;
        if (v >= n) continue;
        int e0 = off[v], e1 = off[v + 1];
        float2 s = __half22float2(y2[(size_t)v * L + fl]);   // self loop
        for (int base = e0; base < e1; base += L) {
            int idx = (base + fl < e1) ? ssrc[base + fl] : 0;
            int cnt = min(L, e1 - base);
            int j = 0;
            for (; j + 4 <= cnt; j += 4) {
                int s0 = __shfl(idx, sub * L + j,     64);
                int s1 = __shfl(idx, sub * L + j + 1, 64);
                int s2 = __shfl(idx, sub * L + j + 2, 64);
                int s3 = __shfl(idx, sub * L + j + 3, 64);
                float2 f0 = __half22float2(y2[(size_t)s0 * L + fl]);
                float2 f1 = __half22float2(y2[(size_t)s1 * L + fl]);
                float2 f2 = __half22float2(y2[(size_t)s2 * L + fl]);
                float2 f3 = __half22float2(y2[(size_t)s3 * L + fl]);
                s.x += (f0.x + f1.x) + (f2.x + f3.x);
                s.y += (f0.y + f1.y) + (f2.y + f3.y);
            }
            for (; j < cnt; j++) {
                int sj = __shfl(idx, sub * L + j, 64);
                float2 f0 = __half22float2(y2[(size_t)sj * L + fl]);
                s.x += f0.x; s.y += f0.y;
            }
        }
        float dv = dinv[v];
        float rx = fmaxf(fmaf(s.x, dv, bv.x), 0.f);
        float ry = fmaxf(fmaf(s.y, dv, bv.y), 0.f);
        H[(size_t)v * L + fl] = ((unsigned)f2bf(ry) << 16) | (unsigned)f2bf(rx);
    }
}

// layer-3 variant: F=16 (L=8), fused mean-pool accumulation, no H write
__global__ __launch_bounds__(TPB) void seg_agg16_pool_h(
    const int* __restrict__ off, const int* __restrict__ ssrc,
    const __half2* __restrict__ y2, const float* __restrict__ dinv,
    const float* __restrict__ b, float* __restrict__ pooled, int n)
{
    constexpr int L = 8;
    const int lane = threadIdx.x & 63;
    const int fl   = lane & 7;
    const int sub  = lane >> 3;
    const int wid  = (blockIdx.x * blockDim.x + threadIdx.x) >> 6;
    const int nw   = (gridDim.x * blockDim.x) >> 6;
    const float2 bv = ((const float2*)b)[fl];
    float2 pacc = make_float2(0.f, 0.f);

    for (int v0 = wid * 8; v0 < n; v0 += nw * 8) {
        int v = v0 + sub;
        if (v >= n) continue;
        int e0 = off[v], e1 = off[v + 1];
        float2 s = __half22float2(y2[(size_t)v * L + fl]);
        for (int base = e0; base < e1; base += L) {
            int idx = (base + fl < e1) ? ssrc[base + fl] : 0;
            int cnt = min(L, e1 - base);
            int j = 0;
            for (; j + 4 <= cnt; j += 4) {
                int s0 = __shfl(idx, sub * L + j,     64);
                int s1 = __shfl(idx, sub * L + j + 1, 64);
                int s2 = __shfl(idx, sub * L + j + 2, 64);
                int s3 = __shfl(idx, sub * L + j + 3, 64);
                float2 f0 = __half22float2(y2[(size_t)s0 * L + fl]);
                float2 f1 = __half22float2(y2[(size_t)s1 * L + fl]);
                float2 f2 = __half22float2(y2[(size_t)s2 * L + fl]);
                float2 f3 = __half22float2(y2[(size_t)s3 * L + fl]);
                s.x += (f0.x + f1.x) + (f2.x + f3.x);
                s.y += (f0.y + f1.y) + (f2.y + f3.y);
            }
            for (; j < cnt; j++) {
                int sj = __shfl(idx, sub * L + j, 64);
                float2 f0 = __half22float2(y2[(size_t)sj * L + fl]);
                s.x += f0.x; s.y += f0.y;
            }
        }
        float dv = dinv[v];
        pacc.x += fmaxf(fmaf(s.x, dv, bv.x), 0.f);
        pacc.y += fmaxf(fmaf(s.y, dv, bv.y), 0.f);
    }
    __shared__ float redx[TPB], redy[TPB];
    redx[threadIdx.x] = pacc.x;
    redy[threadIdx.x] = pacc.y;
    __syncthreads();
    for (int st = 128; st >= 8; st >>= 1) {
        if (threadIdx.x < st) {
            redx[threadIdx.x] += redx[threadIdx.x + st];
            redy[threadIdx.x] += redy[threadIdx.x + st];
        }
        __syncthreads();
    }
    if (threadIdx.x < 8) {
        atomicAdd(&pooled[2 * threadIdx.x],     redx[threadIdx.x]);
        atomicAdd(&pooled[2 * threadIdx.x + 1], redy[threadIdx.x]);
    }
}

// --------------------------------------------------- tiny MLP head + logsoftmax
__global__ void head_kernel(const float* __restrict__ pooled,
                            const float* __restrict__ Wf, const float* __restrict__ bf,
                            const float* __restrict__ Ws, const float* __restrict__ bs,
                            float* __restrict__ out, float invn)
{
    if (threadIdx.x == 0 && blockIdx.x == 0) {
        float p[16], h[8], s[10];
        for (int i = 0; i < 16; i++) p[i] = pooled[i] * invn;
        for (int j = 0; j < 8; j++) {
            float a = bf[j];
            for (int i = 0; i < 16; i++) a = fmaf(p[i], Wf[i * 8 + j], a);
            h[j] = fmaxf(a, 0.f);
        }
        float m = -1e30f;
        for (int c = 0; c < 10; c++) {
            float a = bs[c];
            for (int j = 0; j < 8; j++) a = fmaf(h[j], Ws[j * 10 + c], a);
            s[c] = a;
            m = fmaxf(m, a);
        }
        float lse = 0.f;
        for (int c = 0; c < 10; c++) lse += expf(s[c] - m);
        lse = logf(lse) + m;
        for (int c = 0; c < 10; c++) out[c] = s[c] - lse;
    }
}

static inline size_t align_up(size_t x) { return (x + 255) & ~(size_t)255; }

extern "C" void kernel_launch(void* const* d_in, const int* in_sizes, int n_in,
                              void* d_out, int out_size, void* d_ws, size_t ws_size,
                              hipStream_t stream)
{
    const float* X  = (const float*)d_in[0];
    const int*   ei = (const int*)  d_in[1];
    const float* W1 = (const float*)d_in[2];  const float* b1 = (const float*)d_in[3];
    const float* W2 = (const float*)d_in[4];  const float* b2 = (const float*)d_in[5];
    const float* W3 = (const float*)d_in[6];  const float* b3 = (const float*)d_in[7];
    const float* Wf = (const float*)d_in[8];  const float* bf = (const float*)d_in[9];
    const float* Ws = (const float*)d_in[10]; const float* bs = (const float*)d_in[11];

    const int n = in_sizes[0] / 256;
    const int E = in_sizes[1] / 2;
    const int* src = ei;
    const int* dst = ei + E;
    const int nbkt = (n + BKT_N - 1) / BKT_N;

    // workspace layout
    char* ws = (char*)d_ws;
    size_t off_b = 0;
    int* bcursor = (int*)(ws + off_b);   off_b += align_up(NB_MAX * 4);
    int* boff    = (int*)(ws + off_b);   off_b += align_up((NB_MAX + 1) * 4);
    float* dinv  = (float*)(ws + off_b); off_b += align_up((size_t)n * 4);
    int* off     = (int*)(ws + off_b);   off_b += align_up((size_t)(n + 1) * 4);
    float* pooled= (float*)(ws + off_b); off_b += align_up(16 * 4);
    unsigned short* Wt1 = (unsigned short*)(ws + off_b); off_b += align_up(64 * 256 * 2);
    unsigned short* Wt2 = (unsigned short*)(ws + off_b); off_b += align_up(32 * 64 * 2);
    unsigned short* Wt3 = (unsigned short*)(ws + off_b); off_b += align_up(16 * 32 * 2);
    unsigned int* packed = (unsigned int*)(ws + off_b); off_b += align_up((size_t)nbkt * CAP * 4);
    int* ssrc    = (int*)(ws + off_b);   off_b += align_up((size_t)E * 4);
    __half2* Y   = (__half2*)(ws + off_b); off_b += align_up((size_t)n * 64 * 2);
    unsigned int* H = (unsigned int*)(ws + off_b); off_b += align_up((size_t)n * 64 * 2);

    hipMemsetAsync(pooled, 0, 16 * 4, stream);

    // graph preprocessing (once; reused by all 3 layers)
    init_cursor<<<1, 256, 0, stream>>>(bcursor, nbkt);
    int nchunk = (E + CHUNK - 1) / CHUNK;
    bucket_scatter<<<nchunk, TPB, 0, stream>>>(src, dst, bcursor, packed, E, nbkt);
    bucket_offsets<<<1, 256, 0, stream>>>(bcursor, boff, nbkt, E);
    bucket_csr<<<nbkt, 256, 0, stream>>>(packed, boff, off, dinv, ssrc, n, nbkt);

    // weight conversion (bf16, transposed)
    conv_w<<<16, 256, 0, stream>>>(W1, Wt1, 256, 64);
    conv_w<<<2, 256, 0, stream>>>(W2, Wt2, 64, 32);
    conv_w<<<1, 256, 0, stream>>>(W3, Wt3, 32, 16);

    const int gblk = (n + 127) / 128;

    // ---- layer 1: 256 -> 64
    gemm_mfma<256, 64, float><<<gblk, TPB, 0, stream>>>(X, Wt1, dinv, (__half*)Y, n);
    seg_agg_h<64><<<2048, TPB, 0, stream>>>(off, ssrc, Y, dinv, b1, H, n);

    // ---- layer 2: 64 -> 32
    gemm_mfma<64, 32, unsigned short><<<gblk, TPB, 0, stream>>>(
        (const unsigned short*)H, Wt2, dinv, (__half*)Y, n);
    seg_agg_h<32><<<2048, TPB, 0, stream>>>(off, ssrc, Y, dinv, b2, H, n);

    // ---- layer 3: 32 -> 16 (fused pool)
    gemm_mfma<32, 16, unsigned short><<<gblk, TPB, 0, stream>>>(
        (const unsigned short*)H, Wt3, dinv, (__half*)Y, n);
    seg_agg16_pool_h<<<1024, TPB, 0, stream>>>(off, ssrc, Y, dinv, b3, pooled, n);

    head_kernel<<<1, 64, 0, stream>>>(pooled, Wf, bf, Ws, bs, (float*)d_out, 1.0f / (float)n);
}

// Round 7
// 290.623 us; speedup vs baseline: 5.1639x; 1.0359x over previous
//
#include <hip/hip_runtime.h>
#include <hip/hip_fp16.h>
#include <math.h>

#define TPB 256
#define BKT_SHIFT 9
#define BKT_N 512              // nodes per bucket
#define NB_MAX 256             // max buckets (n <= 131072)
#define CHUNK 4096             // edges per block-chunk in bucket_scatter
#define CAP   24576            // padded packed-region capacity per bucket
#define Y_SCALE 16.0f
#define Y_INV_SCALE (1.0f / 16.0f)

typedef short bf16x8 __attribute__((ext_vector_type(8)));
typedef float f32x4  __attribute__((ext_vector_type(4)));

static __device__ inline unsigned short f2bf(float f) {
    union { float f; unsigned u; } v; v.f = f;
    unsigned r = v.u + 0x7FFF + ((v.u >> 16) & 1);
    return (unsigned short)(r >> 16);
}

static __device__ inline unsigned char f2fp8(float x) {
    int p = __builtin_amdgcn_cvt_pk_fp8_f32(x, x, 0, false);
    return (unsigned char)(p & 0xFF);
}

// ---------------------------------------------------------------- cursor init
__global__ __launch_bounds__(256) void init_cursor(int* __restrict__ bcursor, int nbkt) {
    int t = threadIdx.x;
    if (t < nbkt) bcursor[t] = t * CAP;
}

// ---------------------------------------------------------------- bucketed scatter
// packed edge: (dst_local << 17) | src   (src < 2^17, dst_local < 2^9)
__global__ __launch_bounds__(TPB) void bucket_scatter(
    const int* __restrict__ src, const int* __restrict__ dst,
    int* __restrict__ bcursor, unsigned int* __restrict__ packed, int E, int nbkt)
{
    __shared__ unsigned int  spk[CHUNK];
    __shared__ unsigned char sbk[CHUNK];
    __shared__ int h[NB_MAX];
    __shared__ int base[NB_MAX];
    for (int c0 = blockIdx.x * CHUNK; c0 < E; c0 += gridDim.x * CHUNK) {
        int m = min(CHUNK, E - c0);
        for (int i = threadIdx.x; i < nbkt; i += TPB) h[i] = 0;
        __syncthreads();
        for (int i = threadIdx.x; i < m; i += TPB) {
            int d = dst[c0 + i];
            int s = src[c0 + i];
            int b = d >> BKT_SHIFT;
            spk[i] = ((unsigned)(d & (BKT_N - 1)) << 17) | (unsigned)s;
            sbk[i] = (unsigned char)b;
            atomicAdd(&h[b], 1);
        }
        __syncthreads();
        for (int i = threadIdx.x; i < nbkt; i += TPB) {
            int c = h[i];
            base[i] = c ? atomicAdd(&bcursor[i], c) : 0;
            h[i] = 0;
        }
        __syncthreads();
        for (int i = threadIdx.x; i < m; i += TPB) {
            int b = sbk[i];
            int pos = base[b] + atomicAdd(&h[b], 1);
            packed[pos] = spk[i];
        }
        __syncthreads();
    }
}

// ---------------------------------------------------------------- bucket offsets (1 block)
__global__ __launch_bounds__(256) void bucket_offsets(
    const int* __restrict__ bcursor, int* __restrict__ boff, int nbkt, int E)
{
    int t = threadIdx.x;
    int v = (t < nbkt) ? (bcursor[t] - t * CAP) : 0;
    __shared__ int tmp[256];
    tmp[t] = v; __syncthreads();
    for (int s = 1; s < 256; s <<= 1) {
        int x = (t >= s) ? tmp[t - s] : 0;
        __syncthreads();
        tmp[t] += x;
        __syncthreads();
    }
    if (t < nbkt) boff[t] = tmp[t] - v;
    if (t == 0) boff[nbkt] = E;
}

// ---------------------------------------------------------------- per-bucket CSR
__global__ __launch_bounds__(256) void bucket_csr(
    const unsigned int* __restrict__ packed, const int* __restrict__ boff,
    int* __restrict__ off, float* __restrict__ dinv, int* __restrict__ ssrc,
    int n, int nbkt)
{
    const int b   = blockIdx.x;
    const int e0  = boff[b];
    const int cnt = boff[b + 1] - e0;
    const int p0  = b * CAP;
    const int v0  = b << BKT_SHIFT;
    const int nv  = min(BKT_N, n - v0);
    const int t   = threadIdx.x;

    __shared__ int hist[BKT_N];
    __shared__ int cur[BKT_N];
    __shared__ int tmp[256];

    for (int i = t; i < nv; i += 256) hist[i] = 0;
    __syncthreads();
    for (int e = t; e < cnt; e += 256)
        atomicAdd(&hist[packed[p0 + e] >> 17], 1);
    __syncthreads();

    int a = (2 * t     < nv) ? hist[2 * t]     : 0;
    int c = (2 * t + 1 < nv) ? hist[2 * t + 1] : 0;
    int ps = a + c;
    tmp[t] = ps; __syncthreads();
    for (int s = 1; s < 256; s <<= 1) {
        int x = (t >= s) ? tmp[t - s] : 0;
        __syncthreads();
        tmp[t] += x;
        __syncthreads();
    }
    int ex = tmp[t] - ps;
    if (2 * t < nv) {
        cur[2 * t] = ex;
        off[v0 + 2 * t] = e0 + ex;
        dinv[v0 + 2 * t] = rsqrtf((float)a + 1.0f);
    }
    if (2 * t + 1 < nv) {
        cur[2 * t + 1] = ex + a;
        off[v0 + 2 * t + 1] = e0 + ex + a;
        dinv[v0 + 2 * t + 1] = rsqrtf((float)c + 1.0f);
    }
    if (b == nbkt - 1 && t == 0) off[n] = boff[nbkt];
    __syncthreads();

    for (int e = t; e < cnt; e += 256) {
        unsigned p = packed[p0 + e];
        int dl = p >> 17;
        int s  = p & 0x1FFFF;
        int pos = atomicAdd(&cur[dl], 1);
        ssrc[e0 + pos] = s;
    }
}

// ---------------------------------------------------------------- W -> bf16 transposed
__global__ __launch_bounds__(256) void conv_w(
    const float* __restrict__ W, unsigned short* __restrict__ Wt, int K, int N)
{
    int total = K * N;
    for (int i = threadIdx.x + blockIdx.x * 256; i < total; i += gridDim.x * 256) {
        int k = i / N, c = i % N;
        Wt[c * K + k] = f2bf(W[i]);
    }
}

// ---------------------------------------------------------------- MFMA GEMM
// Yq = fp8((A@W)*dinv[row]*Y_SCALE).  A: fp32 (layer1) or bf16 (H).
template<int K, int NCOL, typename AT>
__global__ __launch_bounds__(TPB) void gemm_mfma(
    const AT* __restrict__ A, const unsigned short* __restrict__ Wt,
    const float* __restrict__ dinv, unsigned char* __restrict__ Yq, int n)
{
    constexpr int NT = NCOL / 16;
    constexpr int KS = K / 32;
    const int lane = threadIdx.x & 63;
    const int w    = threadIdx.x >> 6;
    const int rowbase = blockIdx.x * 128 + w * 32;
    const int arow = lane & 15;
    const int kb   = (lane >> 4) * 8;

    f32x4 acc[2][NT];
#pragma unroll
    for (int mt = 0; mt < 2; mt++)
#pragma unroll
        for (int nt = 0; nt < NT; nt++) acc[mt][nt] = (f32x4)(0.f);

#pragma unroll
    for (int ks = 0; ks < KS; ks++) {
        bf16x8 a[2];
#pragma unroll
        for (int mt = 0; mt < 2; mt++) {
            int r = rowbase + mt * 16 + arow;
            if constexpr (sizeof(AT) == 4) {
                if (r < n) {
                    const float4* p = (const float4*)(A + (size_t)r * K + ks * 32 + kb);
                    float4 u = p[0], v = p[1];
                    a[mt][0] = f2bf(u.x); a[mt][1] = f2bf(u.y);
                    a[mt][2] = f2bf(u.z); a[mt][3] = f2bf(u.w);
                    a[mt][4] = f2bf(v.x); a[mt][5] = f2bf(v.y);
                    a[mt][6] = f2bf(v.z); a[mt][7] = f2bf(v.w);
                } else {
#pragma unroll
                    for (int i = 0; i < 8; i++) a[mt][i] = 0;
                }
            } else {
                if (r < n)
                    a[mt] = *(const bf16x8*)(A + (size_t)r * K + ks * 32 + kb);
                else {
#pragma unroll
                    for (int i = 0; i < 8; i++) a[mt][i] = 0;
                }
            }
        }
        bf16x8 b[NT];
#pragma unroll
        for (int nt = 0; nt < NT; nt++)
            b[nt] = *(const bf16x8*)(Wt + (size_t)(nt * 16 + arow) * K + ks * 32 + kb);
#pragma unroll
        for (int mt = 0; mt < 2; mt++)
#pragma unroll
            for (int nt = 0; nt < NT; nt++)
                acc[mt][nt] = __builtin_amdgcn_mfma_f32_16x16x32_bf16(
                    a[mt], b[nt], acc[mt][nt], 0, 0, 0);
    }

#pragma unroll
    for (int mt = 0; mt < 2; mt++) {
        int r0 = rowbase + mt * 16 + (lane >> 4) * 4;
#pragma unroll
        for (int j = 0; j < 4; j++) {
            int r = r0 + j;
            if (r < n) {
                float dv = dinv[r] * Y_SCALE;
#pragma unroll
                for (int nt = 0; nt < NT; nt++)
                    Yq[(size_t)r * NCOL + nt * 16 + arow] = f2fp8(acc[mt][nt][j] * dv);
            }
        }
    }
}

// ---------------------------------------- pull-mode segment aggregation (fp8 gather)
// L = F/4 lanes per node, each lane loads 4 fp8 features (one uint).
// H[v] = relu(dinv[v]/S*(sum yq[src] + yq[v]) + b), written as 4x bf16 (uint2).
template<int F>
__global__ __launch_bounds__(TPB) void seg_agg_q(
    const int* __restrict__ off, const int* __restrict__ ssrc,
    const unsigned int* __restrict__ Yq, const float* __restrict__ dinv,
    const float* __restrict__ b, uint2* __restrict__ H, int n)
{
    constexpr int L     = F / 4;
    constexpr int LOG2L = (L == 16) ? 4 : (L == 8) ? 3 : 2;
    constexpr int NPW   = 64 / L;
    const int lane = threadIdx.x & 63;
    const int fl   = lane & (L - 1);
    const int sub  = lane >> LOG2L;
    const int wid  = (blockIdx.x * blockDim.x + threadIdx.x) >> 6;
    const int nw   = (gridDim.x * blockDim.x) >> 6;
    const float4 bv = ((const float4*)b)[fl];

    for (int v0 = wid * NPW; v0 < n; v0 += nw * NPW) {
        int v = v0 + sub;
        if (v >= n) continue;
        int e0 = off[v], e1 = off[v + 1];
        unsigned us = Yq[(size_t)v * L + fl];            // self loop
        float4 s;
        s.x = __builtin_amdgcn_cvt_f32_fp8(us, 0);
        s.y = __builtin_amdgcn_cvt_f32_fp8(us, 1);
        s.z = __builtin_amdgcn_cvt_f32_fp8(us, 2);
        s.w = __builtin_amdgcn_cvt_f32_fp8(us, 3);
        for (int base = e0; base < e1; base += L) {
            int idx = (base + fl < e1) ? ssrc[base + fl] : 0;
            int cnt = min(L, e1 - base);
            int j = 0;
            for (; j + 4 <= cnt; j += 4) {
                int s0 = __shfl(idx, sub * L + j,     64);
                int s1 = __shfl(idx, sub * L + j + 1, 64);
                int s2 = __shfl(idx, sub * L + j + 2, 64);
                int s3 = __shfl(idx, sub * L + j + 3, 64);
                unsigned u0 = Yq[(size_t)s0 * L + fl];
                unsigned u1 = Yq[(size_t)s1 * L + fl];
                unsigned u2 = Yq[(size_t)s2 * L + fl];
                unsigned u3 = Yq[(size_t)s3 * L + fl];
                s.x += __builtin_amdgcn_cvt_f32_fp8(u0, 0) + __builtin_amdgcn_cvt_f32_fp8(u1, 0)
                     + __builtin_amdgcn_cvt_f32_fp8(u2, 0) + __builtin_amdgcn_cvt_f32_fp8(u3, 0);
                s.y += __builtin_amdgcn_cvt_f32_fp8(u0, 1) + __builtin_amdgcn_cvt_f32_fp8(u1, 1)
                     + __builtin_amdgcn_cvt_f32_fp8(u2, 1) + __builtin_amdgcn_cvt_f32_fp8(u3, 1);
                s.z += __builtin_amdgcn_cvt_f32_fp8(u0, 2) + __builtin_amdgcn_cvt_f32_fp8(u1, 2)
                     + __builtin_amdgcn_cvt_f32_fp8(u2, 2) + __builtin_amdgcn_cvt_f32_fp8(u3, 2);
                s.w += __builtin_amdgcn_cvt_f32_fp8(u0, 3) + __builtin_amdgcn_cvt_f32_fp8(u1, 3)
                     + __builtin_amdgcn_cvt_f32_fp8(u2, 3) + __builtin_amdgcn_cvt_f32_fp8(u3, 3);
            }
            for (; j < cnt; j++) {
                int sj = __shfl(idx, sub * L + j, 64);
                unsigned u0 = Yq[(size_t)sj * L + fl];
                s.x += __builtin_amdgcn_cvt_f32_fp8(u0, 0);
                s.y += __builtin_amdgcn_cvt_f32_fp8(u0, 1);
                s.z += __builtin_amdgcn_cvt_f32_fp8(u0, 2);
                s.w += __builtin_amdgcn_cvt_f32_fp8(u0, 3);
            }
        }
        float dv = dinv[v] * Y_INV_SCALE;
        float rx = fmaxf(fmaf(s.x, dv, bv.x), 0.f);
        float ry = fmaxf(fmaf(s.y, dv, bv.y), 0.f);
        float rz = fmaxf(fmaf(s.z, dv, bv.z), 0.f);
        float rw = fmaxf(fmaf(s.w, dv, bv.w), 0.f);
        uint2 o;
        o.x = ((unsigned)f2bf(ry) << 16) | (unsigned)f2bf(rx);
        o.y = ((unsigned)f2bf(rw) << 16) | (unsigned)f2bf(rz);
        H[(size_t)v * L + fl] = o;
    }
}

// layer-3 variant: F=16 (L=4), fused mean-pool accumulation, no H write
__global__ __launch_bounds__(TPB) void seg_agg16_pool_q(
    const int* __restrict__ off, const int* __restrict__ ssrc,
    const unsigned int* __restrict__ Yq, const float* __restrict__ dinv,
    const float* __restrict__ b, float* __restrict__ pooled, int n)
{
    constexpr int L = 4;
    const int lane = threadIdx.x & 63;
    const int fl   = lane & 3;
    const int sub  = lane >> 2;
    const int wid  = (blockIdx.x * blockDim.x + threadIdx.x) >> 6;
    const int nw   = (gridDim.x * blockDim.x) >> 6;
    const float4 bv = ((const float4*)b)[fl];
    float4 pacc = make_float4(0.f, 0.f, 0.f, 0.f);

    for (int v0 = wid * 16; v0 < n; v0 += nw * 16) {
        int v = v0 + sub;
        if (v >= n) continue;
        int e0 = off[v], e1 = off[v + 1];
        unsigned us = Yq[(size_t)v * L + fl];
        float4 s;
        s.x = __builtin_amdgcn_cvt_f32_fp8(us, 0);
        s.y = __builtin_amdgcn_cvt_f32_fp8(us, 1);
        s.z = __builtin_amdgcn_cvt_f32_fp8(us, 2);
        s.w = __builtin_amdgcn_cvt_f32_fp8(us, 3);
        for (int base = e0; base < e1; base += L) {
            int idx = (base + fl < e1) ? ssrc[base + fl] : 0;
            int cnt = min(L, e1 - base);
            int j = 0;
            for (; j + 4 <= cnt; j += 4) {
                int s0 = __shfl(idx, sub * L + j,     64);
                int s1 = __shfl(idx, sub * L + j + 1, 64);
                int s2 = __shfl(idx, sub * L + j + 2, 64);
                int s3 = __shfl(idx, sub * L + j + 3, 64);
                unsigned u0 = Yq[(size_t)s0 * L + fl];
                unsigned u1 = Yq[(size_t)s1 * L + fl];
                unsigned u2 = Yq[(size_t)s2 * L + fl];
                unsigned u3 = Yq[(size_t)s3 * L + fl];
                s.x += __builtin_amdgcn_cvt_f32_fp8(u0, 0) + __builtin_amdgcn_cvt_f32_fp8(u1, 0)
                     + __builtin_amdgcn_cvt_f32_fp8(u2, 0) + __builtin_amdgcn_cvt_f32_fp8(u3, 0);
                s.y += __builtin_amdgcn_cvt_f32_fp8(u0, 1) + __builtin_amdgcn_cvt_f32_fp8(u1, 1)
                     + __builtin_amdgcn_cvt_f32_fp8(u2, 1) + __builtin_amdgcn_cvt_f32_fp8(u3, 1);
                s.z += __builtin_amdgcn_cvt_f32_fp8(u0, 2) + __builtin_amdgcn_cvt_f32_fp8(u1, 2)
                     + __builtin_amdgcn_cvt_f32_fp8(u2, 2) + __builtin_amdgcn_cvt_f32_fp8(u3, 2);
                s.w += __builtin_amdgcn_cvt_f32_fp8(u0, 3) + __builtin_amdgcn_cvt_f32_fp8(u1, 3)
                     + __builtin_amdgcn_cvt_f32_fp8(u2, 3) + __builtin_amdgcn_cvt_f32_fp8(u3, 3);
            }
            for (; j < cnt; j++) {
                int sj = __shfl(idx, sub * L + j, 64);
                unsigned u0 = Yq[(size_t)sj * L + fl];
                s.x += __builtin_amdgcn_cvt_f32_fp8(u0, 0);
                s.y += __builtin_amdgcn_cvt_f32_fp8(u0, 1);
                s.z += __builtin_amdgcn_cvt_f32_fp8(u0, 2);
                s.w += __builtin_amdgcn_cvt_f32_fp8(u0, 3);
            }
        }
        float dv = dinv[v] * Y_INV_SCALE;
        pacc.x += fmaxf(fmaf(s.x, dv, bv.x), 0.f);
        pacc.y += fmaxf(fmaf(s.y, dv, bv.y), 0.f);
        pacc.z += fmaxf(fmaf(s.z, dv, bv.z), 0.f);
        pacc.w += fmaxf(fmaf(s.w, dv, bv.w), 0.f);
    }
    __shared__ float4 red[TPB];
    red[threadIdx.x] = pacc;
    __syncthreads();
    for (int st = 128; st >= 4; st >>= 1) {
        if (threadIdx.x < st) {
            float4 o = red[threadIdx.x + st];
            red[threadIdx.x].x += o.x;
            red[threadIdx.x].y += o.y;
            red[threadIdx.x].z += o.z;
            red[threadIdx.x].w += o.w;
        }
        __syncthreads();
    }
    if (threadIdx.x < 4) {
        float4 o = red[threadIdx.x];
        atomicAdd(&pooled[4 * threadIdx.x + 0], o.x);
        atomicAdd(&pooled[4 * threadIdx.x + 1], o.y);
        atomicAdd(&pooled[4 * threadIdx.x + 2], o.z);
        atomicAdd(&pooled[4 * threadIdx.x + 3], o.w);
    }
}

// --------------------------------------------------- tiny MLP head + logsoftmax
__global__ void head_kernel(const float* __restrict__ pooled,
                            const float* __restrict__ Wf, const float* __restrict__ bf,
                            const float* __restrict__ Ws, const float* __restrict__ bs,
                            float* __restrict__ out, float invn)
{
    if (threadIdx.x == 0 && blockIdx.x == 0) {
        float p[16], h[8], s[10];
        for (int i = 0; i < 16; i++) p[i] = pooled[i] * invn;
        for (int j = 0; j < 8; j++) {
            float a = bf[j];
            for (int i = 0; i < 16; i++) a = fmaf(p[i], Wf[i * 8 + j], a);
            h[j] = fmaxf(a, 0.f);
        }
        float m = -1e30f;
        for (int c = 0; c < 10; c++) {
            float a = bs[c];
            for (int j = 0; j < 8; j++) a = fmaf(h[j], Ws[j * 10 + c], a);
            s[c] = a;
            m = fmaxf(m, a);
        }
        float lse = 0.f;
        for (int c = 0; c < 10; c++) lse += expf(s[c] - m);
        lse = logf(lse) + m;
        for (int c = 0; c < 10; c++) out[c] = s[c] - lse;
    }
}

static inline size_t align_up(size_t x) { return (x + 255) & ~(size_t)255; }

extern "C" void kernel_launch(void* const* d_in, const int* in_sizes, int n_in,
                              void* d_out, int out_size, void* d_ws, size_t ws_size,
                              hipStream_t stream)
{
    const float* X  = (const float*)d_in[0];
    const int*   ei = (const int*)  d_in[1];
    const float* W1 = (const float*)d_in[2];  const float* b1 = (const float*)d_in[3];
    const float* W2 = (const float*)d_in[4];  const float* b2 = (const float*)d_in[5];
    const float* W3 = (const float*)d_in[6];  const float* b3 = (const float*)d_in[7];
    const float* Wf = (const float*)d_in[8];  const float* bf = (const float*)d_in[9];
    const float* Ws = (const float*)d_in[10]; const float* bs = (const float*)d_in[11];

    const int n = in_sizes[0] / 256;
    const int E = in_sizes[1] / 2;
    const int* src = ei;
    const int* dst = ei + E;
    const int nbkt = (n + BKT_N - 1) / BKT_N;

    // workspace layout
    char* ws = (char*)d_ws;
    size_t off_b = 0;
    int* bcursor = (int*)(ws + off_b);   off_b += align_up(NB_MAX * 4);
    int* boff    = (int*)(ws + off_b);   off_b += align_up((NB_MAX + 1) * 4);
    float* dinv  = (float*)(ws + off_b); off_b += align_up((size_t)n * 4);
    int* off     = (int*)(ws + off_b);   off_b += align_up((size_t)(n + 1) * 4);
    float* pooled= (float*)(ws + off_b); off_b += align_up(16 * 4);
    unsigned short* Wt1 = (unsigned short*)(ws + off_b); off_b += align_up(64 * 256 * 2);
    unsigned short* Wt2 = (unsigned short*)(ws + off_b); off_b += align_up(32 * 64 * 2);
    unsigned short* Wt3 = (unsigned short*)(ws + off_b); off_b += align_up(16 * 32 * 2);
    unsigned int* packed = (unsigned int*)(ws + off_b); off_b += align_up((size_t)nbkt * CAP * 4);
    int* ssrc    = (int*)(ws + off_b);   off_b += align_up((size_t)E * 4);
    unsigned char* Yq = (unsigned char*)(ws + off_b); off_b += align_up((size_t)n * 64);
    uint2* H     = (uint2*)(ws + off_b); off_b += align_up((size_t)n * 64 * 2);

    hipMemsetAsync(pooled, 0, 16 * 4, stream);

    // graph preprocessing (once; reused by all 3 layers)
    init_cursor<<<1, 256, 0, stream>>>(bcursor, nbkt);
    int nchunk = (E + CHUNK - 1) / CHUNK;
    bucket_scatter<<<nchunk, TPB, 0, stream>>>(src, dst, bcursor, packed, E, nbkt);
    bucket_offsets<<<1, 256, 0, stream>>>(bcursor, boff, nbkt, E);
    bucket_csr<<<nbkt, 256, 0, stream>>>(packed, boff, off, dinv, ssrc, n, nbkt);

    // weight conversion (bf16, transposed)
    conv_w<<<16, 256, 0, stream>>>(W1, Wt1, 256, 64);
    conv_w<<<2, 256, 0, stream>>>(W2, Wt2, 64, 32);
    conv_w<<<1, 256, 0, stream>>>(W3, Wt3, 32, 16);

    const int gblk = (n + 127) / 128;

    // ---- layer 1: 256 -> 64
    gemm_mfma<256, 64, float><<<gblk, TPB, 0, stream>>>(X, Wt1, dinv, Yq, n);
    seg_agg_q<64><<<2048, TPB, 0, stream>>>(off, ssrc, (const unsigned int*)Yq, dinv, b1, H, n);

    // ---- layer 2: 64 -> 32
    gemm_mfma<64, 32, unsigned short><<<gblk, TPB, 0, stream>>>(
        (const unsigned short*)H, Wt2, dinv, Yq, n);
    seg_agg_q<32><<<2048, TPB, 0, stream>>>(off, ssrc, (const unsigned int*)Yq, dinv, b2, H, n);

    // ---- layer 3: 32 -> 16 (fused pool)
    gemm_mfma<32, 16, unsigned short><<<gblk, TPB, 0, stream>>>(
        (const unsigned short*)H, Wt3, dinv, Yq, n);
    seg_agg16_pool_q<<<1024, TPB, 0, stream>>>(off, ssrc, (const unsigned int*)Yq, dinv, b3, pooled, n);

    head_kernel<<<1, 64, 0, stream>>>(pooled, Wf, bf, Ws, bs, (float*)d_out, 1.0f / (float)n);
}

// Round 8
// 274.930 us; speedup vs baseline: 5.4587x; 1.0571x over previous
//
#include <hip/hip_runtime.h>
#include <hip/hip_fp16.h>
#include <math.h>

#define TPB 256
#define BKT_SHIFT 9
#define BKT_N 512              // nodes per bucket
#define NB_MAX 256             // max buckets (n <= 131072)
#define CHUNK 4096             // edges per block-chunk in bucket_scatter
#define CAP   24576            // padded packed-region capacity per bucket
#define Y_SCALE 16.0f
#define Y_INV_SCALE (1.0f / 16.0f)

typedef short bf16x8 __attribute__((ext_vector_type(8)));
typedef float f32x4  __attribute__((ext_vector_type(4)));

static __device__ inline unsigned short f2bf(float f) {
    union { float f; unsigned u; } v; v.f = f;
    unsigned r = v.u + 0x7FFF + ((v.u >> 16) & 1);
    return (unsigned short)(r >> 16);
}

static __device__ inline unsigned char f2fp8(float x) {
    int p = __builtin_amdgcn_cvt_pk_fp8_f32(x, x, 0, false);
    return (unsigned char)(p & 0xFF);
}

// ---------------------------------------------------------------- cursor init
__global__ __launch_bounds__(256) void init_cursor(int* __restrict__ bcursor, int nbkt) {
    int t = threadIdx.x;
    if (t < nbkt) bcursor[t] = t * CAP;
}

// ---------------------------------------------------------------- bucketed scatter
// packed edge: (dst_local << 17) | src   (src < 2^17, dst_local < 2^9)
__global__ __launch_bounds__(TPB) void bucket_scatter(
    const int* __restrict__ src, const int* __restrict__ dst,
    int* __restrict__ bcursor, unsigned int* __restrict__ packed, int E, int nbkt)
{
    __shared__ unsigned int  spk[CHUNK];
    __shared__ unsigned char sbk[CHUNK];
    __shared__ int h[NB_MAX];
    __shared__ int base[NB_MAX];
    for (int c0 = blockIdx.x * CHUNK; c0 < E; c0 += gridDim.x * CHUNK) {
        int m = min(CHUNK, E - c0);
        for (int i = threadIdx.x; i < nbkt; i += TPB) h[i] = 0;
        __syncthreads();
        for (int i = threadIdx.x; i < m; i += TPB) {
            int d = dst[c0 + i];
            int s = src[c0 + i];
            int b = d >> BKT_SHIFT;
            spk[i] = ((unsigned)(d & (BKT_N - 1)) << 17) | (unsigned)s;
            sbk[i] = (unsigned char)b;
            atomicAdd(&h[b], 1);
        }
        __syncthreads();
        for (int i = threadIdx.x; i < nbkt; i += TPB) {
            int c = h[i];
            base[i] = c ? atomicAdd(&bcursor[i], c) : 0;
            h[i] = 0;
        }
        __syncthreads();
        for (int i = threadIdx.x; i < m; i += TPB) {
            int b = sbk[i];
            int pos = base[b] + atomicAdd(&h[b], 1);
            packed[pos] = spk[i];
        }
        __syncthreads();
    }
}

// ---------------------------------------------------------------- bucket offsets (1 block)
__global__ __launch_bounds__(256) void bucket_offsets(
    const int* __restrict__ bcursor, int* __restrict__ boff, int nbkt, int E)
{
    int t = threadIdx.x;
    int v = (t < nbkt) ? (bcursor[t] - t * CAP) : 0;
    __shared__ int tmp[256];
    tmp[t] = v; __syncthreads();
    for (int s = 1; s < 256; s <<= 1) {
        int x = (t >= s) ? tmp[t - s] : 0;
        __syncthreads();
        tmp[t] += x;
        __syncthreads();
    }
    if (t < nbkt) boff[t] = tmp[t] - v;
    if (t == 0) boff[nbkt] = E;
}

// ---------------------------------------------------------------- per-bucket CSR
__global__ __launch_bounds__(256) void bucket_csr(
    const unsigned int* __restrict__ packed, const int* __restrict__ boff,
    int* __restrict__ off, float* __restrict__ dinv, int* __restrict__ ssrc,
    int n, int nbkt)
{
    const int b   = blockIdx.x;
    const int e0  = boff[b];
    const int cnt = boff[b + 1] - e0;
    const int p0  = b * CAP;
    const int v0  = b << BKT_SHIFT;
    const int nv  = min(BKT_N, n - v0);
    const int t   = threadIdx.x;

    __shared__ int hist[BKT_N];
    __shared__ int cur[BKT_N];
    __shared__ int tmp[256];

    for (int i = t; i < nv; i += 256) hist[i] = 0;
    __syncthreads();
    for (int e = t; e < cnt; e += 256)
        atomicAdd(&hist[packed[p0 + e] >> 17], 1);
    __syncthreads();

    int a = (2 * t     < nv) ? hist[2 * t]     : 0;
    int c = (2 * t + 1 < nv) ? hist[2 * t + 1] : 0;
    int ps = a + c;
    tmp[t] = ps; __syncthreads();
    for (int s = 1; s < 256; s <<= 1) {
        int x = (t >= s) ? tmp[t - s] : 0;
        __syncthreads();
        tmp[t] += x;
        __syncthreads();
    }
    int ex = tmp[t] - ps;
    if (2 * t < nv) {
        cur[2 * t] = ex;
        off[v0 + 2 * t] = e0 + ex;
        dinv[v0 + 2 * t] = rsqrtf((float)a + 1.0f);
    }
    if (2 * t + 1 < nv) {
        cur[2 * t + 1] = ex + a;
        off[v0 + 2 * t + 1] = e0 + ex + a;
        dinv[v0 + 2 * t + 1] = rsqrtf((float)c + 1.0f);
    }
    if (b == nbkt - 1 && t == 0) off[n] = boff[nbkt];
    __syncthreads();

    for (int e = t; e < cnt; e += 256) {
        unsigned p = packed[p0 + e];
        int dl = p >> 17;
        int s  = p & 0x1FFFF;
        int pos = atomicAdd(&cur[dl], 1);
        ssrc[e0 + pos] = s;
    }
}

// ---------------------------------------------------------------- W -> bf16 transposed
__global__ __launch_bounds__(256) void conv_w(
    const float* __restrict__ W, unsigned short* __restrict__ Wt, int K, int N)
{
    int total = K * N;
    for (int i = threadIdx.x + blockIdx.x * 256; i < total; i += gridDim.x * 256) {
        int k = i / N, c = i % N;
        Wt[c * K + k] = f2bf(W[i]);
    }
}

// ---------------------------------------------------------------- MFMA GEMM
// Yq = fp8((A@W)*dinv[row]*Y_SCALE).  A: fp32 (layer1) or bf16 (H).
template<int K, int NCOL, typename AT>
__global__ __launch_bounds__(TPB) void gemm_mfma(
    const AT* __restrict__ A, const unsigned short* __restrict__ Wt,
    const float* __restrict__ dinv, unsigned char* __restrict__ Yq, int n)
{
    constexpr int NT = NCOL / 16;
    constexpr int KS = K / 32;
    const int lane = threadIdx.x & 63;
    const int w    = threadIdx.x >> 6;
    const int rowbase = blockIdx.x * 128 + w * 32;
    const int arow = lane & 15;
    const int kb   = (lane >> 4) * 8;

    f32x4 acc[2][NT];
#pragma unroll
    for (int mt = 0; mt < 2; mt++)
#pragma unroll
        for (int nt = 0; nt < NT; nt++) acc[mt][nt] = (f32x4)(0.f);

#pragma unroll
    for (int ks = 0; ks < KS; ks++) {
        bf16x8 a[2];
#pragma unroll
        for (int mt = 0; mt < 2; mt++) {
            int r = rowbase + mt * 16 + arow;
            if constexpr (sizeof(AT) == 4) {
                if (r < n) {
                    const float4* p = (const float4*)(A + (size_t)r * K + ks * 32 + kb);
                    float4 u = p[0], v = p[1];
                    a[mt][0] = f2bf(u.x); a[mt][1] = f2bf(u.y);
                    a[mt][2] = f2bf(u.z); a[mt][3] = f2bf(u.w);
                    a[mt][4] = f2bf(v.x); a[mt][5] = f2bf(v.y);
                    a[mt][6] = f2bf(v.z); a[mt][7] = f2bf(v.w);
                } else {
#pragma unroll
                    for (int i = 0; i < 8; i++) a[mt][i] = 0;
                }
            } else {
                if (r < n)
                    a[mt] = *(const bf16x8*)(A + (size_t)r * K + ks * 32 + kb);
                else {
#pragma unroll
                    for (int i = 0; i < 8; i++) a[mt][i] = 0;
                }
            }
        }
        bf16x8 b[NT];
#pragma unroll
        for (int nt = 0; nt < NT; nt++)
            b[nt] = *(const bf16x8*)(Wt + (size_t)(nt * 16 + arow) * K + ks * 32 + kb);
#pragma unroll
        for (int mt = 0; mt < 2; mt++)
#pragma unroll
            for (int nt = 0; nt < NT; nt++)
                acc[mt][nt] = __builtin_amdgcn_mfma_f32_16x16x32_bf16(
                    a[mt], b[nt], acc[mt][nt], 0, 0, 0);
    }

#pragma unroll
    for (int mt = 0; mt < 2; mt++) {
        int r0 = rowbase + mt * 16 + (lane >> 4) * 4;
#pragma unroll
        for (int j = 0; j < 4; j++) {
            int r = r0 + j;
            if (r < n) {
                float dv = dinv[r] * Y_SCALE;
#pragma unroll
                for (int nt = 0; nt < NT; nt++)
                    Yq[(size_t)r * NCOL + nt * 16 + arow] = f2fp8(acc[mt][nt][j] * dv);
            }
        }
    }
}

// ---------------------------------------- lane-per-node segment aggregation (fp8 rows)
// Lane owns node v: gathers whole Yq rows (F/4 uints each), fp32 accumulate,
// fused relu(dinv*(sum+self)+b). POOL=true also block-reduces the mean-pool.
template<int F, bool POOL>
__global__ __launch_bounds__(TPB) void seg_node(
    const int* __restrict__ off, const int* __restrict__ ssrc,
    const unsigned char* __restrict__ Yq, const float* __restrict__ dinv,
    const float* __restrict__ bias, unsigned int* __restrict__ H,
    float* __restrict__ pooled, int n)
{
    constexpr int NU = F / 4;      // uint words per row
    constexpr int U  = 4;          // edge unroll
    const int v = blockIdx.x * TPB + threadIdx.x;

    float acc[F];
#pragma unroll
    for (int i = 0; i < F; i++) acc[i] = 0.f;
    float r16[16];
    if constexpr (POOL) {
#pragma unroll
        for (int i = 0; i < 16; i++) r16[i] = 0.f;
    }

    if (v < n) {
        // self loop
        {
            const unsigned int* yp = (const unsigned int*)(Yq + (size_t)v * F);
#pragma unroll
            for (int wn = 0; wn < NU; wn++) {
                unsigned u = yp[wn];
                acc[4 * wn + 0] += __builtin_amdgcn_cvt_f32_fp8(u, 0);
                acc[4 * wn + 1] += __builtin_amdgcn_cvt_f32_fp8(u, 1);
                acc[4 * wn + 2] += __builtin_amdgcn_cvt_f32_fp8(u, 2);
                acc[4 * wn + 3] += __builtin_amdgcn_cvt_f32_fp8(u, 3);
            }
        }
        int e0 = off[v], e1 = off[v + 1];
        int e = e0;
        for (; e + U <= e1; e += U) {
            unsigned rw[U][NU];
#pragma unroll
            for (int k = 0; k < U; k++) {
                const unsigned int* yp = (const unsigned int*)(Yq + (size_t)ssrc[e + k] * F);
#pragma unroll
                for (int wn = 0; wn < NU; wn++) rw[k][wn] = yp[wn];
            }
#pragma unroll
            for (int k = 0; k < U; k++)
#pragma unroll
                for (int wn = 0; wn < NU; wn++) {
                    unsigned u = rw[k][wn];
                    acc[4 * wn + 0] += __builtin_amdgcn_cvt_f32_fp8(u, 0);
                    acc[4 * wn + 1] += __builtin_amdgcn_cvt_f32_fp8(u, 1);
                    acc[4 * wn + 2] += __builtin_amdgcn_cvt_f32_fp8(u, 2);
                    acc[4 * wn + 3] += __builtin_amdgcn_cvt_f32_fp8(u, 3);
                }
        }
        for (; e < e1; e++) {
            const unsigned int* yp = (const unsigned int*)(Yq + (size_t)ssrc[e] * F);
#pragma unroll
            for (int wn = 0; wn < NU; wn++) {
                unsigned u = yp[wn];
                acc[4 * wn + 0] += __builtin_amdgcn_cvt_f32_fp8(u, 0);
                acc[4 * wn + 1] += __builtin_amdgcn_cvt_f32_fp8(u, 1);
                acc[4 * wn + 2] += __builtin_amdgcn_cvt_f32_fp8(u, 2);
                acc[4 * wn + 3] += __builtin_amdgcn_cvt_f32_fp8(u, 3);
            }
        }

        float dv = dinv[v] * Y_INV_SCALE;
        if constexpr (!POOL) {
            unsigned int* hp = H + (size_t)v * (F / 2);
#pragma unroll
            for (int i = 0; i < F; i += 2) {
                float rx = fmaxf(fmaf(acc[i],     dv, bias[i]),     0.f);
                float ry = fmaxf(fmaf(acc[i + 1], dv, bias[i + 1]), 0.f);
                hp[i / 2] = ((unsigned)f2bf(ry) << 16) | (unsigned)f2bf(rx);
            }
        } else {
#pragma unroll
            for (int i = 0; i < 16; i++)
                r16[i] = fmaxf(fmaf(acc[i], dv, bias[i]), 0.f);
        }
    }

    if constexpr (POOL) {
        __shared__ float red[TPB][17];
#pragma unroll
        for (int i = 0; i < 16; i++) red[threadIdx.x][i] = r16[i];
        __syncthreads();
        for (int st = 128; st >= 1; st >>= 1) {
            if (threadIdx.x < st) {
#pragma unroll
                for (int i = 0; i < 16; i++)
                    red[threadIdx.x][i] += red[threadIdx.x + st][i];
            }
            __syncthreads();
        }
        if (threadIdx.x < 16) atomicAdd(&pooled[threadIdx.x], red[0][threadIdx.x]);
    }
}

// --------------------------------------------------- tiny MLP head + logsoftmax
__global__ void head_kernel(const float* __restrict__ pooled,
                            const float* __restrict__ Wf, const float* __restrict__ bf,
                            const float* __restrict__ Ws, const float* __restrict__ bs,
                            float* __restrict__ out, float invn)
{
    if (threadIdx.x == 0 && blockIdx.x == 0) {
        float p[16], h[8], s[10];
        for (int i = 0; i < 16; i++) p[i] = pooled[i] * invn;
        for (int j = 0; j < 8; j++) {
            float a = bf[j];
            for (int i = 0; i < 16; i++) a = fmaf(p[i], Wf[i * 8 + j], a);
            h[j] = fmaxf(a, 0.f);
        }
        float m = -1e30f;
        for (int c = 0; c < 10; c++) {
            float a = bs[c];
            for (int j = 0; j < 8; j++) a = fmaf(h[j], Ws[j * 10 + c], a);
            s[c] = a;
            m = fmaxf(m, a);
        }
        float lse = 0.f;
        for (int c = 0; c < 10; c++) lse += expf(s[c] - m);
        lse = logf(lse) + m;
        for (int c = 0; c < 10; c++) out[c] = s[c] - lse;
    }
}

static inline size_t align_up(size_t x) { return (x + 255) & ~(size_t)255; }

extern "C" void kernel_launch(void* const* d_in, const int* in_sizes, int n_in,
                              void* d_out, int out_size, void* d_ws, size_t ws_size,
                              hipStream_t stream)
{
    const float* X  = (const float*)d_in[0];
    const int*   ei = (const int*)  d_in[1];
    const float* W1 = (const float*)d_in[2];  const float* b1 = (const float*)d_in[3];
    const float* W2 = (const float*)d_in[4];  const float* b2 = (const float*)d_in[5];
    const float* W3 = (const float*)d_in[6];  const float* b3 = (const float*)d_in[7];
    const float* Wf = (const float*)d_in[8];  const float* bf = (const float*)d_in[9];
    const float* Ws = (const float*)d_in[10]; const float* bs = (const float*)d_in[11];

    const int n = in_sizes[0] / 256;
    const int E = in_sizes[1] / 2;
    const int* src = ei;
    const int* dst = ei + E;
    const int nbkt = (n + BKT_N - 1) / BKT_N;

    // workspace layout
    char* ws = (char*)d_ws;
    size_t off_b = 0;
    int* bcursor = (int*)(ws + off_b);   off_b += align_up(NB_MAX * 4);
    int* boff    = (int*)(ws + off_b);   off_b += align_up((NB_MAX + 1) * 4);
    float* dinv  = (float*)(ws + off_b); off_b += align_up((size_t)n * 4);
    int* off     = (int*)(ws + off_b);   off_b += align_up((size_t)(n + 1) * 4);
    float* pooled= (float*)(ws + off_b); off_b += align_up(16 * 4);
    unsigned short* Wt1 = (unsigned short*)(ws + off_b); off_b += align_up(64 * 256 * 2);
    unsigned short* Wt2 = (unsigned short*)(ws + off_b); off_b += align_up(32 * 64 * 2);
    unsigned short* Wt3 = (unsigned short*)(ws + off_b); off_b += align_up(16 * 32 * 2);
    unsigned int* packed = (unsigned int*)(ws + off_b); off_b += align_up((size_t)nbkt * CAP * 4);
    int* ssrc    = (int*)(ws + off_b);   off_b += align_up((size_t)E * 4);
    unsigned char* Yq = (unsigned char*)(ws + off_b); off_b += align_up((size_t)n * 64);
    unsigned int* H = (unsigned int*)(ws + off_b); off_b += align_up((size_t)n * 64 * 2);

    hipMemsetAsync(pooled, 0, 16 * 4, stream);

    // graph preprocessing (once; reused by all 3 layers)
    init_cursor<<<1, 256, 0, stream>>>(bcursor, nbkt);
    int nchunk = (E + CHUNK - 1) / CHUNK;
    bucket_scatter<<<nchunk, TPB, 0, stream>>>(src, dst, bcursor, packed, E, nbkt);
    bucket_offsets<<<1, 256, 0, stream>>>(bcursor, boff, nbkt, E);
    bucket_csr<<<nbkt, 256, 0, stream>>>(packed, boff, off, dinv, ssrc, n, nbkt);

    // weight conversion (bf16, transposed)
    conv_w<<<16, 256, 0, stream>>>(W1, Wt1, 256, 64);
    conv_w<<<2, 256, 0, stream>>>(W2, Wt2, 64, 32);
    conv_w<<<1, 256, 0, stream>>>(W3, Wt3, 32, 16);

    const int gblk = (n + 127) / 128;
    const int nblk = (n + TPB - 1) / TPB;

    // ---- layer 1: 256 -> 64
    gemm_mfma<256, 64, float><<<gblk, TPB, 0, stream>>>(X, Wt1, dinv, Yq, n);
    seg_node<64, false><<<nblk, TPB, 0, stream>>>(off, ssrc, Yq, dinv, b1, H, nullptr, n);

    // ---- layer 2: 64 -> 32
    gemm_mfma<64, 32, unsigned short><<<gblk, TPB, 0, stream>>>(
        (const unsigned short*)H, Wt2, dinv, Yq, n);
    seg_node<32, false><<<nblk, TPB, 0, stream>>>(off, ssrc, Yq, dinv, b2, H, nullptr, n);

    // ---- layer 3: 32 -> 16 (fused pool)
    gemm_mfma<32, 16, unsigned short><<<gblk, TPB, 0, stream>>>(
        (const unsigned short*)H, Wt3, dinv, Yq, n);
    seg_node<16, true><<<nblk, TPB, 0, stream>>>(off, ssrc, Yq, dinv, b3, nullptr, pooled, n);

    head_kernel<<<1, 64, 0, stream>>>(pooled, Wf, bf, Ws, bs, (float*)d_out, 1.0f / (float)n);
}